// Round 3
// baseline (915.338 us; speedup 1.0000x reference)
//
#include <hip/hip_runtime.h>
#include <hip/hip_bf16.h>
#include <math.h>

typedef unsigned short u16;
typedef __attribute__((ext_vector_type(8))) short short8;
typedef __attribute__((ext_vector_type(4))) float floatx4;

#define DEVINL __device__ __forceinline__

DEVINL u16 f2bf(float f) {
  union { unsigned int i; float f; } v; v.f = f;
  unsigned int i = v.i;
  unsigned int r = (i + 0x7fffu + ((i >> 16) & 1u)) >> 16;
  return (u16)r;
}

// ---------------------------------------------------------------------------
// cvt: f32 -> bf16 elementwise (weights). n multiple of 4.
// ---------------------------------------------------------------------------
__global__ __launch_bounds__(256) void k_cvt(const float* __restrict__ src,
                                             u16* __restrict__ dst, int n4) {
  int i = blockIdx.x * 256 + threadIdx.x;
  if (i >= n4) return;
  float4 v = ((const float4*)src)[i];
  ushort4 o;
  o.x = f2bf(v.x); o.y = f2bf(v.y); o.z = f2bf(v.z); o.w = f2bf(v.w);
  ((ushort4*)dst)[i] = o;
}

// ---------------------------------------------------------------------------
// K0: transpose+convert x[b][c][n] (f32) -> xT[b][n][c] (bf16), 64x64 tiles
// ---------------------------------------------------------------------------
__global__ __launch_bounds__(256) void k_transpose(const float* __restrict__ x,
                                                   u16* __restrict__ xT,
                                                   int nC, int nN) {
  __shared__ u16 tile[64 * 65];  // +1 u16 pad per row
  int b = blockIdx.z;
  int c0 = blockIdx.y * 64, n0 = blockIdx.x * 64;
  const float* xb = x + ((long)b * nC + c0) * nN + n0;
  u16* xTb = xT + ((long)b * nN + n0) * nC + c0;
  int tid = threadIdx.x;
#pragma unroll
  for (int p = 0; p < 2; ++p) {
    int u = tid + p * 256;
    int r = u >> 3, nc = (u & 7) * 8;
    const float4* srcp = (const float4*)(xb + (long)r * nN + nc);
    float4 v0 = srcp[0], v1 = srcp[1];
    int base = r * 65 + nc;
    tile[base + 0] = f2bf(v0.x); tile[base + 1] = f2bf(v0.y);
    tile[base + 2] = f2bf(v0.z); tile[base + 3] = f2bf(v0.w);
    tile[base + 4] = f2bf(v1.x); tile[base + 5] = f2bf(v1.y);
    tile[base + 6] = f2bf(v1.z); tile[base + 7] = f2bf(v1.w);
  }
  __syncthreads();
#pragma unroll
  for (int p = 0; p < 2; ++p) {
    int u = tid + p * 256;
    int nr = u >> 3, cc = (u & 7) * 8;
    __align__(16) u16 tmp[8];
#pragma unroll
    for (int j = 0; j < 8; ++j) tmp[j] = tile[(cc + j) * 65 + nr];
    *(uint4*)(xTb + (long)nr * nC + cc) = *(uint4*)tmp;
  }
}

// ---------------------------------------------------------------------------
// gemm_bt: Out[M,N] = A[M,K] * B[Ncols,K]^T (+bias, relu), bf16 in, fp32 acc
// 128x128 tile, 4 waves, 16x16x32 bf16 MFMA. Conservative staging: guarded
// uint4 VGPR-roundtrip loads, zero-fill OOB rows (all LDS bytes written).
// BIAS_MODE: 0 none, 1 row (bias1[row]), 2 col (select bias1/bias2 by nSplit).
// ---------------------------------------------------------------------------
template <bool OUT_F32, int BIAS_MODE, bool RELU>
__global__ __launch_bounds__(256) void k_gemm_bt(
    const u16* __restrict__ A, int lda, long aBS,
    const u16* __restrict__ B1, const u16* __restrict__ B2, int nSplit,
    int ldb, long bBS,
    void* __restrict__ Out, int ldo, long oBS,
    const float* __restrict__ bias1, const float* __restrict__ bias2,
    int M, int N, int K) {
  __shared__ __align__(16) u16 As[128 * 32];
  __shared__ __align__(16) u16 Bs[128 * 32];
  int bz = blockIdx.z;
  int m0 = blockIdx.y * 128, n0 = blockIdx.x * 128;
  const u16* Ablk = A + (long)bz * aBS + (long)m0 * lda;
  const u16* Bblk =
      ((n0 < nSplit) ? (B1 + (long)n0 * ldb) : (B2 + (long)(n0 - nSplit) * ldb)) +
      (long)bz * bBS;
  int tid = threadIdx.x;
  int lane = tid & 63;
  int lane16 = lane & 15, quad = lane >> 4;
  int wid = tid >> 6;
  int wm = wid >> 1, wn = wid & 1;

  floatx4 acc[4][4];
#pragma unroll
  for (int i = 0; i < 4; ++i)
#pragma unroll
    for (int j = 0; j < 4; ++j) acc[i][j] = (floatx4){0.f, 0.f, 0.f, 0.f};

  for (int k0 = 0; k0 < K; k0 += 32) {
    __syncthreads();
#pragma unroll
    for (int h = 0; h < 2; ++h) {
      int pp = tid + h * 256;
      int r = pp >> 2, kk = (pp & 3) * 8;
      uint4 va = make_uint4(0u, 0u, 0u, 0u);
      if (m0 + r < M) va = *(const uint4*)(Ablk + (long)r * lda + k0 + kk);
      *(uint4*)&As[r * 32 + kk] = va;
      uint4 vb = make_uint4(0u, 0u, 0u, 0u);
      if (n0 + r < N) vb = *(const uint4*)(Bblk + (long)r * ldb + k0 + kk);
      *(uint4*)&Bs[r * 32 + kk] = vb;
    }
    __syncthreads();
    short8 af[4], bfr[4];
#pragma unroll
    for (int t = 0; t < 4; ++t)
      af[t] = *(const short8*)&As[(wm * 64 + t * 16 + lane16) * 32 + quad * 8];
#pragma unroll
    for (int t = 0; t < 4; ++t)
      bfr[t] = *(const short8*)&Bs[(wn * 64 + t * 16 + lane16) * 32 + quad * 8];
#pragma unroll
    for (int i = 0; i < 4; ++i)
#pragma unroll
      for (int j = 0; j < 4; ++j)
        acc[i][j] = __builtin_amdgcn_mfma_f32_16x16x32_bf16(af[i], bfr[j],
                                                            acc[i][j], 0, 0, 0);
  }

  // epilogue: C/D layout col=lane&15, row=quad*4+reg  [m89-verified]
  const float* bcolPtr = bias1;
  int bofs = 0;
  if (BIAS_MODE == 2 && n0 >= nSplit) { bcolPtr = bias2; bofs = nSplit; }
#pragma unroll
  for (int i = 0; i < 4; ++i) {
    int rowb = m0 + wm * 64 + i * 16 + quad * 4;
#pragma unroll
    for (int j = 0; j < 4; ++j) {
      int col = n0 + wn * 64 + j * 16 + lane16;
      if (col >= N) continue;
      float bc = 0.f;
      if (BIAS_MODE == 2) bc = bcolPtr[col - bofs];
#pragma unroll
      for (int r = 0; r < 4; ++r) {
        int row = rowb + r;
        if (row >= M) continue;
        float v = acc[i][j][r];
        if (BIAS_MODE == 2) v += bc;
        if (BIAS_MODE == 1) v += bias1[row];
        if (RELU) v = fmaxf(v, 0.f);
        if (OUT_F32)
          ((float*)Out)[(long)bz * oBS + (long)row * ldo + col] = v;
        else
          ((u16*)Out)[(long)bz * oBS + (long)row * ldo + col] = f2bf(v);
      }
    }
  }
}

// ---------------------------------------------------------------------------
// K3: log-space Sinkhorn, one block per batch. scores fp32 [b][64][1024].
// ---------------------------------------------------------------------------
__global__ __launch_bounds__(1024) void k_sinkhorn(
    const float* __restrict__ S, const float* __restrict__ alphaPtr,
    float lmu, float lmu_bin, float lnu, float norm, u16* __restrict__ P) {
  __shared__ float u_[65];
  __shared__ float v_[1024];
  int b = blockIdx.x, tid = threadIdx.x;
  const float* Sb = S + (long)b * 65536;
  float alpha = *alphaPtr;
  v_[tid] = 0.f;
  __syncthreads();
  int wid = tid >> 6, lane = tid & 63;
  for (int it = 0; it < 3; ++it) {
    for (int i = wid; i < 65; i += 16) {   // u-pass: wave per row
      float vals[16];
      float mx = -3.4e38f;
#pragma unroll
      for (int s = 0; s < 16; ++s) {
        int j = lane + s * 64;
        float z = (i < 64 ? Sb[i * 1024 + j] : alpha) + v_[j];
        vals[s] = z;
        mx = fmaxf(mx, z);
      }
#pragma unroll
      for (int off = 32; off > 0; off >>= 1) mx = fmaxf(mx, __shfl_xor(mx, off));
      float sum = 0.f;
#pragma unroll
      for (int s = 0; s < 16; ++s) sum += __expf(vals[s] - mx);
#pragma unroll
      for (int off = 32; off > 0; off >>= 1) sum += __shfl_xor(sum, off);
      if (lane == 0) u_[i] = (i < 64 ? lmu : lmu_bin) - (mx + __logf(sum));
    }
    __syncthreads();
    {  // v-pass: thread per column, online LSE over m=65
      float mx = -3.4e38f, sum = 0.f;
      for (int i = 0; i < 65; ++i) {
        float z = (i < 64 ? Sb[i * 1024 + tid] : alpha) + u_[i];
        if (z > mx) { sum = sum * __expf(mx - z) + 1.f; mx = z; }
        else sum += __expf(z - mx);
      }
      v_[tid] = lnu - (mx + __logf(sum));
    }
    __syncthreads();
  }
  float vj = v_[tid];
  u16* Pb = P + (long)b * 65536;
  for (int i = 0; i < 64; ++i) {
    float z = Sb[i * 1024 + tid] + u_[i] + vj - norm;
    Pb[i * 1024 + tid] = f2bf(__expf(fminf(z, 1.0f)));  // z<=0 mathematically
  }
}

// ---------------------------------------------------------------------------
// K5: token MLP (f32) + agg column l2norm + global l2norm + output (f32)
// ---------------------------------------------------------------------------
DEVINL float blockSum256(float x, float* red) {
#pragma unroll
  for (int off = 32; off > 0; off >>= 1) x += __shfl_xor(x, off);
  int wid = threadIdx.x >> 6;
  __syncthreads();
  if ((threadIdx.x & 63) == 0) red[wid] = x;
  __syncthreads();
  return red[0] + red[1] + red[2] + red[3];
}

DEVINL float waveSum(float x) {
#pragma unroll
  for (int off = 32; off > 0; off >>= 1) x += __shfl_xor(x, off);
  return x;
}

__global__ __launch_bounds__(256) void k_finalize(
    const float* __restrict__ t, const float* __restrict__ w1,
    const float* __restrict__ b1, const float* __restrict__ w2,
    const float* __restrict__ b2, const float* __restrict__ agg,
    float* __restrict__ out) {
  __shared__ float tl[1536];
  __shared__ float h1[512];
  __shared__ float tk[256];
  __shared__ float cn[64];
  __shared__ float red[4];
  int b = blockIdx.x, tid = threadIdx.x;
  int wid = tid >> 6, lane = tid & 63;
  for (int i = tid; i < 1536; i += 256) tl[i] = t[b * 1536 + i];
  __syncthreads();
  // layer 1: wave per output row, coalesced weight reads
  for (int o = wid; o < 512; o += 4) {
    const float* wr = w1 + (long)o * 1536;
    float acc = 0.f;
#pragma unroll
    for (int s = 0; s < 24; ++s) { int c = lane + s * 64; acc += tl[c] * wr[c]; }
    acc = waveSum(acc);
    if (lane == 0) h1[o] = fmaxf(acc + b1[o], 0.f);
  }
  __syncthreads();
  // layer 2: wave per output row
  for (int o = wid; o < 256; o += 4) {
    const float* wr = w2 + (long)o * 512;
    float acc = 0.f;
#pragma unroll
    for (int s = 0; s < 8; ++s) { int c = lane + s * 64; acc += h1[c] * wr[c]; }
    acc = waveSum(acc);
    if (lane == 0) tk[o] = acc + b2[o];
  }
  __syncthreads();
  float tkv = tk[tid];
  float tss = blockSum256(tkv * tkv, red);
  float tn = fmaxf(sqrtf(tss), 1e-12f);
  const float* ab = agg + (long)b * 8192;
  if (tid < 64) {
    float s = 0.f;
    for (int l = 0; l < 128; ++l) { float a = ab[l * 64 + tid]; s += a * a; }
    cn[tid] = fmaxf(sqrtf(s), 1e-12f);
  }
  __syncthreads();
  float gs = (tkv / tn) * (tkv / tn);
  for (int idx = tid; idx < 8192; idx += 256) {
    float a = ab[idx] / cn[idx & 63];
    gs += a * a;
  }
  float G = blockSum256(gs, red);
  float inv = 1.f / fmaxf(sqrtf(G), 1e-12f);
  float* ob = out + (long)b * 8448;
  ob[tid] = tkv / tn * inv;
  for (int idx = tid; idx < 8192; idx += 256)
    ob[256 + idx] = ab[idx] / cn[idx & 63] * inv;
}

// ---------------------------------------------------------------------------
extern "C" void kernel_launch(void* const* d_in, const int* in_sizes, int n_in,
                              void* d_out, int out_size, void* d_ws,
                              size_t ws_size, hipStream_t stream) {
  const float* x = (const float*)d_in[0];
  const float* t = (const float*)d_in[1];
  const float* cf_w1 = (const float*)d_in[2];
  const float* cf_b1 = (const float*)d_in[3];
  const float* cf_w2 = (const float*)d_in[4];
  const float* cf_b2 = (const float*)d_in[5];
  const float* sc_w1 = (const float*)d_in[6];
  const float* sc_b1 = (const float*)d_in[7];
  const float* sc_w2 = (const float*)d_in[8];
  const float* sc_b2 = (const float*)d_in[9];
  const float* tk_w1 = (const float*)d_in[10];
  const float* tk_b1 = (const float*)d_in[11];
  const float* tk_w2 = (const float*)d_in[12];
  const float* tk_b2 = (const float*)d_in[13];
  const float* dust = (const float*)d_in[14];
  float* out = (float*)d_out;

  // workspace layout (all 16B-multiples)
  char* ws = (char*)d_ws;
  size_t off = 0;
  u16* wc1 = (u16*)(ws + off); off += (size_t)512 * 1536 * 2;       // cf_w1 bf16
  u16* ws1 = (u16*)(ws + off); off += (size_t)512 * 1536 * 2;       // sc_w1 bf16
  u16* wc2 = (u16*)(ws + off); off += (size_t)128 * 512 * 2;        // cf_w2 bf16
  u16* ws2 = (u16*)(ws + off); off += (size_t)64 * 512 * 2;         // sc_w2 bf16
  u16* f = (u16*)(ws + off);   off += (size_t)32 * 128 * 1024 * 2;  // 8 MB
  float* scr = (float*)(ws + off); off += (size_t)32 * 64 * 1024 * 4;  // 8 MB
  u16* P = (u16*)(ws + off);   off += (size_t)32 * 64 * 1024 * 2;   // 4 MB
  float* agg = (float*)(ws + off); off += (size_t)32 * 128 * 64 * 4;   // 1 MB
  size_t fixed = off;
  size_t perB = (size_t)1024 * 1536 * 2 + (size_t)1024 * 1024 * 2;  // xT+hT
  int c = 1;
  const int cands[6] = {32, 16, 8, 4, 2, 1};
  for (int k = 0; k < 6; ++k)
    if (fixed + (size_t)cands[k] * perB <= ws_size) { c = cands[k]; break; }
  u16* xT = (u16*)(ws + fixed);
  u16* hT = (u16*)(ws + fixed + (size_t)c * 1024 * 1536 * 2);

  // convert weights to bf16
  k_cvt<<<768, 256, 0, stream>>>(cf_w1, wc1, 512 * 1536 / 4);
  k_cvt<<<768, 256, 0, stream>>>(sc_w1, ws1, 512 * 1536 / 4);
  k_cvt<<<64, 256, 0, stream>>>(cf_w2, wc2, 128 * 512 / 4);
  k_cvt<<<32, 256, 0, stream>>>(sc_w2, ws2, 64 * 512 / 4);

  float norm = -logf(1088.f);          // -log(m+n), m=64 n=1024
  float lmu = norm;
  float lmu_bin = logf(960.f) + norm;  // log(n-m) + norm
  float lnu = norm;

  for (int cb = 0; cb < 32; cb += c) {
    // K0: x[b][c][n] f32 -> xT[b][n][c] bf16
    k_transpose<<<dim3(16, 24, c), 256, 0, stream>>>(
        x + (size_t)cb * 1536 * 1024, xT, 1536, 1024);
    // K1: hT[b][n][o] = relu(xT . W1^T + b1), fused cf(o<512) + sc(o>=512)
    k_gemm_bt<false, 2, true><<<dim3(8, 8, c), 256, 0, stream>>>(
        xT, 1536, (long)1024 * 1536,
        wc1, ws1, 512, 1536, 0,
        hT, 1024, (long)1024 * 1024,
        cf_b1, sc_b1, 1024, 1024, 1536);
    // K2a: f[b][l][n] = cf_w2 . hT_cf^T + cf_b2   (bf16 out)
    k_gemm_bt<false, 1, false><<<dim3(8, 1, c), 256, 0, stream>>>(
        wc2, 512, 0,
        hT, hT, 1 << 30, 1024, (long)1024 * 1024,
        f + (size_t)cb * 128 * 1024, 1024, (long)128 * 1024,
        cf_b2, cf_b2, 128, 1024, 512);
    // K2b: scores[b][m][n] = sc_w2 . hT_sc^T + sc_b2   (fp32 out)
    k_gemm_bt<true, 1, false><<<dim3(8, 1, c), 256, 0, stream>>>(
        ws2, 512, 0,
        hT + 512, hT + 512, 1 << 30, 1024, (long)1024 * 1024,
        scr + (size_t)cb * 64 * 1024, 1024, (long)64 * 1024,
        sc_b2, sc_b2, 64, 1024, 512);
  }
  // K3: Sinkhorn -> P bf16 [b][64][1024]
  k_sinkhorn<<<32, 1024, 0, stream>>>(scr, dust, lmu, lmu_bin, lnu, norm, P);
  // K4: agg[b][l][m] = sum_n f[l][n] P[m][n]   (fp32 out)
  k_gemm_bt<true, 0, false><<<dim3(1, 1, 32), 256, 0, stream>>>(
      f, 1024, (long)128 * 1024,
      P, P, 1 << 30, 1024, (long)64 * 1024,
      agg, 64, (long)128 * 64,
      (const float*)nullptr, (const float*)nullptr, 128, 64, 1024);
  // K5: token MLP + norms + output
  k_finalize<<<32, 256, 0, stream>>>(t, tk_w1, tk_b1, tk_w2, tk_b2, agg, out);
}

// Round 4
// 853.388 us; speedup vs baseline: 1.0726x; 1.0726x over previous
//
#include <hip/hip_runtime.h>
#include <hip/hip_bf16.h>
#include <math.h>

typedef unsigned short u16;
typedef __attribute__((ext_vector_type(8))) short short8;
typedef __attribute__((ext_vector_type(4))) float floatx4;

#define DEVINL __device__ __forceinline__

DEVINL float bf2f(u16 u) { union { unsigned int i; float f; } v; v.i = ((unsigned int)u) << 16; return v.f; }
DEVINL u16 f2bf(float f) {
  union { unsigned int i; float f; } v; v.f = f;
  unsigned int i = v.i;
  unsigned int r = (i + 0x7fffu + ((i >> 16) & 1u)) >> 16;
  return (u16)r;
}

// ---------------------------------------------------------------------------
// cvt: f32 -> bf16 elementwise (weights). n multiple of 4.
// ---------------------------------------------------------------------------
__global__ __launch_bounds__(256) void k_cvt(const float* __restrict__ src,
                                             u16* __restrict__ dst, int n4) {
  int i = blockIdx.x * 256 + threadIdx.x;
  if (i >= n4) return;
  float4 v = ((const float4*)src)[i];
  ushort4 o;
  o.x = f2bf(v.x); o.y = f2bf(v.y); o.z = f2bf(v.z); o.w = f2bf(v.w);
  ((ushort4*)dst)[i] = o;
}

// ---------------------------------------------------------------------------
// K0: transpose+convert x[b][c][n] (f32) -> xT[b][n][c] (bf16), 64x64 tiles
// ---------------------------------------------------------------------------
__global__ __launch_bounds__(256) void k_transpose(const float* __restrict__ x,
                                                   u16* __restrict__ xT,
                                                   int nC, int nN) {
  __shared__ u16 tile[64 * 65];  // +1 u16 pad per row
  int b = blockIdx.z;
  int c0 = blockIdx.y * 64, n0 = blockIdx.x * 64;
  const float* xb = x + ((long)b * nC + c0) * nN + n0;
  u16* xTb = xT + ((long)b * nN + n0) * nC + c0;
  int tid = threadIdx.x;
#pragma unroll
  for (int p = 0; p < 2; ++p) {
    int u = tid + p * 256;
    int r = u >> 3, nc = (u & 7) * 8;
    const float4* srcp = (const float4*)(xb + (long)r * nN + nc);
    float4 v0 = srcp[0], v1 = srcp[1];
    int base = r * 65 + nc;
    tile[base + 0] = f2bf(v0.x); tile[base + 1] = f2bf(v0.y);
    tile[base + 2] = f2bf(v0.z); tile[base + 3] = f2bf(v0.w);
    tile[base + 4] = f2bf(v1.x); tile[base + 5] = f2bf(v1.y);
    tile[base + 6] = f2bf(v1.z); tile[base + 7] = f2bf(v1.w);
  }
  __syncthreads();
#pragma unroll
  for (int p = 0; p < 2; ++p) {
    int u = tid + p * 256;
    int nr = u >> 3, cc = (u & 7) * 8;
    __align__(16) u16 tmp[8];
#pragma unroll
    for (int j = 0; j < 8; ++j) tmp[j] = tile[(cc + j) * 65 + nr];
    *(uint4*)(xTb + (long)nr * nC + cc) = *(uint4*)(tmp);
  }
}

// ---------------------------------------------------------------------------
// gemm_bt: Out[M,N] = A[M,K] * B[Ncols,K]^T (+bias, relu), bf16 in, fp32 acc
// m97 structure: 128x128 tile, 4 waves, 16x16x32 bf16 MFMA, width-16
// global_load_lds staging (unconditional; OOB tile rows CLAMP to last valid
// row — duplicates are discarded by the epilogue guards, LDS never stale).
// BIAS_MODE: 0 none, 1 row (bias1[row]), 2 col (select bias1/bias2 by nSplit).
// ---------------------------------------------------------------------------
template <bool OUT_F32, int BIAS_MODE, bool RELU>
__global__ __launch_bounds__(256) void k_gemm_bt(
    const u16* __restrict__ A, int lda, long aBS,
    const u16* __restrict__ B1, const u16* __restrict__ B2, int nSplit,
    int ldb, long bBS,
    void* __restrict__ Out, int ldo, long oBS,
    const float* __restrict__ bias1, const float* __restrict__ bias2,
    int M, int N, int K) {
  __shared__ __align__(16) u16 As[128 * 32];
  __shared__ __align__(16) u16 Bs[128 * 32];
  int bz = blockIdx.z;
  int m0 = blockIdx.y * 128, n0 = blockIdx.x * 128;
  const u16* Ablk = A + (long)bz * aBS + (long)m0 * lda;
  const u16* Bblk =
      ((n0 < nSplit) ? (B1 + (long)n0 * ldb) : (B2 + (long)(n0 - nSplit) * ldb)) +
      (long)bz * bBS;
  int tid = threadIdx.x;
  int lane = tid & 63;
  int lane16 = lane & 15, quad = lane >> 4;
  int wid = tid >> 6;
  int wm = wid >> 1, wn = wid & 1;

  // staging geometry: chunk ch (16 rows, 1KB); this wave owns chunks 2w,2w+1.
  // lane -> row ch*16 + lane/4, 16B piece (lane&3). LDS dest = base + lane*16.
  int rA0 = (lane >> 2);
  int kk = (lane & 3) * 8;
  int mMax = M - 1 - m0, nMax = N - 1 - n0;

  floatx4 acc[4][4];
#pragma unroll
  for (int i = 0; i < 4; ++i)
#pragma unroll
    for (int j = 0; j < 4; ++j) acc[i][j] = (floatx4){0.f, 0.f, 0.f, 0.f};

  for (int k0 = 0; k0 < K; k0 += 32) {
    __syncthreads();  // previous compute done before LDS overwrite
#pragma unroll
    for (int h = 0; h < 2; ++h) {
      int ch = wid * 2 + h;
      int r = ch * 16 + rA0;
      int ra = min(r, mMax);
      const u16* srcA = Ablk + (long)ra * lda + k0 + kk;
      __builtin_amdgcn_global_load_lds(
          (const __attribute__((address_space(1))) void*)srcA,
          (__attribute__((address_space(3))) void*)&As[ch * 512], 16, 0, 0);
      int rb = min(r, nMax);
      const u16* srcB = Bblk + (long)rb * ldb + k0 + kk;
      __builtin_amdgcn_global_load_lds(
          (const __attribute__((address_space(1))) void*)srcB,
          (__attribute__((address_space(3))) void*)&Bs[ch * 512], 16, 0, 0);
    }
    __syncthreads();  // drains vmcnt: LDS tiles ready
    short8 af[4], bfr[4];
#pragma unroll
    for (int t = 0; t < 4; ++t)
      af[t] = *(const short8*)&As[(wm * 64 + t * 16 + lane16) * 32 + quad * 8];
#pragma unroll
    for (int t = 0; t < 4; ++t)
      bfr[t] = *(const short8*)&Bs[(wn * 64 + t * 16 + lane16) * 32 + quad * 8];
#pragma unroll
    for (int i = 0; i < 4; ++i)
#pragma unroll
      for (int j = 0; j < 4; ++j)
        acc[i][j] = __builtin_amdgcn_mfma_f32_16x16x32_bf16(af[i], bfr[j],
                                                            acc[i][j], 0, 0, 0);
  }

  // epilogue: C/D layout col=lane&15, row=quad*4+reg  [m89-verified]
  const float* bcolPtr = bias1;
  int bofs = 0;
  if (BIAS_MODE == 2 && n0 >= nSplit) { bcolPtr = bias2; bofs = nSplit; }
#pragma unroll
  for (int i = 0; i < 4; ++i) {
    int rowb = m0 + wm * 64 + i * 16 + quad * 4;
#pragma unroll
    for (int j = 0; j < 4; ++j) {
      int col = n0 + wn * 64 + j * 16 + lane16;
      if (col >= N) continue;
      float bc = 0.f;
      if (BIAS_MODE == 2) bc = bcolPtr[col - bofs];
#pragma unroll
      for (int r = 0; r < 4; ++r) {
        int row = rowb + r;
        if (row >= M) continue;
        float v = acc[i][j][r];
        if (BIAS_MODE == 2) v += bc;
        if (BIAS_MODE == 1) v += bias1[row];
        if (RELU) v = fmaxf(v, 0.f);
        if (OUT_F32)
          ((float*)Out)[(long)bz * oBS + (long)row * ldo + col] = v;
        else
          ((u16*)Out)[(long)bz * oBS + (long)row * ldo + col] = f2bf(v);
      }
    }
  }
}

// ---------------------------------------------------------------------------
// K3: log-space Sinkhorn, one block per batch. scores bf16 [b][64][1024].
// ---------------------------------------------------------------------------
__global__ __launch_bounds__(1024) void k_sinkhorn(
    const u16* __restrict__ S, const float* __restrict__ alphaPtr,
    float lmu, float lmu_bin, float lnu, float norm, u16* __restrict__ P) {
  __shared__ float u_[65];
  __shared__ float v_[1024];
  int b = blockIdx.x, tid = threadIdx.x;
  const u16* Sb = S + (long)b * 65536;
  float alpha = *alphaPtr;
  v_[tid] = 0.f;
  __syncthreads();
  int wid = tid >> 6, lane = tid & 63;
  for (int it = 0; it < 3; ++it) {
    for (int i = wid; i < 65; i += 16) {   // u-pass: wave per row
      float vals[16];
      float mx = -3.4e38f;
#pragma unroll
      for (int s = 0; s < 16; ++s) {
        int j = lane + s * 64;
        float z = (i < 64 ? bf2f(Sb[i * 1024 + j]) : alpha) + v_[j];
        vals[s] = z;
        mx = fmaxf(mx, z);
      }
#pragma unroll
      for (int off = 32; off > 0; off >>= 1) mx = fmaxf(mx, __shfl_xor(mx, off));
      float sum = 0.f;
#pragma unroll
      for (int s = 0; s < 16; ++s) sum += __expf(vals[s] - mx);
#pragma unroll
      for (int off = 32; off > 0; off >>= 1) sum += __shfl_xor(sum, off);
      if (lane == 0) u_[i] = (i < 64 ? lmu : lmu_bin) - (mx + __logf(sum));
    }
    __syncthreads();
    {  // v-pass: thread per column, online LSE over m=65
      float mx = -3.4e38f, sum = 0.f;
      for (int i = 0; i < 65; ++i) {
        float z = (i < 64 ? bf2f(Sb[i * 1024 + tid]) : alpha) + u_[i];
        if (z > mx) { sum = sum * __expf(mx - z) + 1.f; mx = z; }
        else sum += __expf(z - mx);
      }
      v_[tid] = lnu - (mx + __logf(sum));
    }
    __syncthreads();
  }
  float vj = v_[tid];
  u16* Pb = P + (long)b * 65536;
  for (int i = 0; i < 64; ++i) {
    float z = bf2f(Sb[i * 1024 + tid]) + u_[i] + vj - norm;
    Pb[i * 1024 + tid] = f2bf(__expf(fminf(z, 1.0f)));  // z<=0 mathematically
  }
}

// ---------------------------------------------------------------------------
// K5: token MLP (f32) + agg column l2norm + global l2norm + output (f32)
// ---------------------------------------------------------------------------
DEVINL float blockSum256(float x, float* red) {
#pragma unroll
  for (int off = 32; off > 0; off >>= 1) x += __shfl_xor(x, off);
  int wid = threadIdx.x >> 6;
  __syncthreads();
  if ((threadIdx.x & 63) == 0) red[wid] = x;
  __syncthreads();
  return red[0] + red[1] + red[2] + red[3];
}

DEVINL float waveSum(float x) {
#pragma unroll
  for (int off = 32; off > 0; off >>= 1) x += __shfl_xor(x, off);
  return x;
}

__global__ __launch_bounds__(256) void k_finalize(
    const float* __restrict__ t, const float* __restrict__ w1,
    const float* __restrict__ b1, const float* __restrict__ w2,
    const float* __restrict__ b2, const float* __restrict__ agg,
    float* __restrict__ out) {
  __shared__ float tl[1536];
  __shared__ float h1[512];
  __shared__ float tk[256];
  __shared__ float cn[64];
  __shared__ float red[4];
  int b = blockIdx.x, tid = threadIdx.x;
  int wid = tid >> 6, lane = tid & 63;
  for (int i = tid; i < 1536; i += 256) tl[i] = t[b * 1536 + i];
  __syncthreads();
  for (int o = wid; o < 512; o += 4) {   // layer 1: wave per output row
    const float* wr = w1 + (long)o * 1536;
    float acc = 0.f;
#pragma unroll
    for (int s = 0; s < 24; ++s) { int c = lane + s * 64; acc += tl[c] * wr[c]; }
    acc = waveSum(acc);
    if (lane == 0) h1[o] = fmaxf(acc + b1[o], 0.f);
  }
  __syncthreads();
  for (int o = wid; o < 256; o += 4) {   // layer 2: wave per output row
    const float* wr = w2 + (long)o * 512;
    float acc = 0.f;
#pragma unroll
    for (int s = 0; s < 8; ++s) { int c = lane + s * 64; acc += h1[c] * wr[c]; }
    acc = waveSum(acc);
    if (lane == 0) tk[o] = acc + b2[o];
  }
  __syncthreads();
  float tkv = tk[tid];
  float tss = blockSum256(tkv * tkv, red);
  float tn = fmaxf(sqrtf(tss), 1e-12f);
  const float* ab = agg + (long)b * 8192;
  if (tid < 64) {
    float s = 0.f;
    for (int l = 0; l < 128; ++l) { float a = ab[l * 64 + tid]; s += a * a; }
    cn[tid] = fmaxf(sqrtf(s), 1e-12f);
  }
  __syncthreads();
  float gs = (tkv / tn) * (tkv / tn);
  for (int idx = tid; idx < 8192; idx += 256) {
    float a = ab[idx] / cn[idx & 63];
    gs += a * a;
  }
  float G = blockSum256(gs, red);
  float inv = 1.f / fmaxf(sqrtf(G), 1e-12f);
  float* ob = out + (long)b * 8448;
  ob[tid] = tkv / tn * inv;
  for (int idx = tid; idx < 8192; idx += 256)
    ob[256 + idx] = ab[idx] / cn[idx & 63] * inv;
}

// ---------------------------------------------------------------------------
extern "C" void kernel_launch(void* const* d_in, const int* in_sizes, int n_in,
                              void* d_out, int out_size, void* d_ws,
                              size_t ws_size, hipStream_t stream) {
  const float* x = (const float*)d_in[0];
  const float* t = (const float*)d_in[1];
  const float* cf_w1 = (const float*)d_in[2];
  const float* cf_b1 = (const float*)d_in[3];
  const float* cf_w2 = (const float*)d_in[4];
  const float* cf_b2 = (const float*)d_in[5];
  const float* sc_w1 = (const float*)d_in[6];
  const float* sc_b1 = (const float*)d_in[7];
  const float* sc_w2 = (const float*)d_in[8];
  const float* sc_b2 = (const float*)d_in[9];
  const float* tk_w1 = (const float*)d_in[10];
  const float* tk_b1 = (const float*)d_in[11];
  const float* tk_w2 = (const float*)d_in[12];
  const float* tk_b2 = (const float*)d_in[13];
  const float* dust = (const float*)d_in[14];
  float* out = (float*)d_out;

  // workspace layout (all 16B-multiples)
  char* ws = (char*)d_ws;
  size_t off = 0;
  u16* wc1 = (u16*)(ws + off); off += (size_t)512 * 1536 * 2;       // cf_w1 bf16
  u16* ws1 = (u16*)(ws + off); off += (size_t)512 * 1536 * 2;       // sc_w1 bf16
  u16* wc2 = (u16*)(ws + off); off += (size_t)128 * 512 * 2;        // cf_w2 bf16
  u16* ws2 = (u16*)(ws + off); off += (size_t)64 * 512 * 2;         // sc_w2 bf16
  u16* f = (u16*)(ws + off);   off += (size_t)32 * 128 * 1024 * 2;  // 8 MB
  u16* scr = (u16*)(ws + off); off += (size_t)32 * 64 * 1024 * 2;   // 4 MB (bf16)
  u16* P = (u16*)(ws + off);   off += (size_t)32 * 64 * 1024 * 2;   // 4 MB
  float* agg = (float*)(ws + off); off += (size_t)32 * 128 * 64 * 4;   // 1 MB
  size_t fixed = off;
  size_t perB = (size_t)1024 * 1536 * 2 + (size_t)1024 * 1024 * 2;  // xT+hT
  int c = 1;
  const int cands[6] = {32, 16, 8, 4, 2, 1};
  for (int k = 0; k < 6; ++k)
    if (fixed + (size_t)cands[k] * perB <= ws_size) { c = cands[k]; break; }
  u16* xT = (u16*)(ws + fixed);
  u16* hT = (u16*)(ws + fixed + (size_t)c * 1024 * 1536 * 2);

  // convert weights to bf16
  k_cvt<<<768, 256, 0, stream>>>(cf_w1, wc1, 512 * 1536 / 4);
  k_cvt<<<768, 256, 0, stream>>>(sc_w1, ws1, 512 * 1536 / 4);
  k_cvt<<<64, 256, 0, stream>>>(cf_w2, wc2, 128 * 512 / 4);
  k_cvt<<<32, 256, 0, stream>>>(sc_w2, ws2, 64 * 512 / 4);

  float norm = -logf(1088.f);          // -log(m+n), m=64 n=1024
  float lmu = norm;
  float lmu_bin = logf(960.f) + norm;  // log(n-m) + norm
  float lnu = norm;

  for (int cb = 0; cb < 32; cb += c) {
    // K0: x[b][c][n] f32 -> xT[b][n][c] bf16
    k_transpose<<<dim3(16, 24, c), 256, 0, stream>>>(
        x + (size_t)cb * 1536 * 1024, xT, 1536, 1024);
    // K1: hT[b][n][o] = relu(xT . W1^T + b1), fused cf(o<512) + sc(o>=512)
    k_gemm_bt<false, 2, true><<<dim3(8, 8, c), 256, 0, stream>>>(
        xT, 1536, (long)1024 * 1536,
        wc1, ws1, 512, 1536, 0,
        hT, 1024, (long)1024 * 1024,
        cf_b1, sc_b1, 1024, 1024, 1536);
    // K2a: f[b][l][n] = cf_w2 . hT_cf^T + cf_b2   (bf16 out)
    k_gemm_bt<false, 1, false><<<dim3(8, 1, c), 256, 0, stream>>>(
        wc2, 512, 0,
        hT, hT, 1 << 30, 1024, (long)1024 * 1024,
        f + (size_t)cb * 128 * 1024, 1024, (long)128 * 1024,
        cf_b2, cf_b2, 128, 1024, 512);
    // K2b: scores[b][m][n] = sc_w2 . hT_sc^T + sc_b2   (bf16 out)
    k_gemm_bt<false, 1, false><<<dim3(8, 1, c), 256, 0, stream>>>(
        ws2, 512, 0,
        hT + 512, hT + 512, 1 << 30, 1024, (long)1024 * 1024,
        scr + (size_t)cb * 64 * 1024, 1024, (long)64 * 1024,
        sc_b2, sc_b2, 64, 1024, 512);
  }
  // K3: Sinkhorn -> P bf16 [b][64][1024]
  k_sinkhorn<<<32, 1024, 0, stream>>>(scr, dust, lmu, lmu_bin, lnu, norm, P);
  // K4: agg[b][l][m] = sum_n f[l][n] P[m][n]   (fp32 out)
  k_gemm_bt<true, 0, false><<<dim3(1, 1, 32), 256, 0, stream>>>(
      f, 1024, (long)128 * 1024,
      P, P, 1 << 30, 1024, (long)64 * 1024,
      agg, 64, (long)128 * 64,
      (const float*)nullptr, (const float*)nullptr, 128, 64, 1024);
  // K5: token MLP + norms + output
  k_finalize<<<32, 256, 0, stream>>>(t, tk_w1, tk_b1, tk_w2, tk_b2, agg, out);
}

// Round 5
// 679.686 us; speedup vs baseline: 1.3467x; 1.2556x over previous
//
#include <hip/hip_runtime.h>
#include <hip/hip_bf16.h>
#include <math.h>

typedef unsigned short u16;
typedef __attribute__((ext_vector_type(8))) short short8;
typedef __attribute__((ext_vector_type(4))) float floatx4;

#define DEVINL __device__ __forceinline__

DEVINL float bf2f(u16 u) { union { unsigned int i; float f; } v; v.i = ((unsigned int)u) << 16; return v.f; }
DEVINL u16 f2bf(float f) {
  union { unsigned int i; float f; } v; v.f = f;
  unsigned int i = v.i;
  unsigned int r = (i + 0x7fffu + ((i >> 16) & 1u)) >> 16;
  return (u16)r;
}

// ---------------------------------------------------------------------------
// cvt: f32 -> bf16 elementwise (weights). n multiple of 4.
// ---------------------------------------------------------------------------
__global__ __launch_bounds__(256) void k_cvt(const float* __restrict__ src,
                                             u16* __restrict__ dst, int n4) {
  int i = blockIdx.x * 256 + threadIdx.x;
  if (i >= n4) return;
  float4 v = ((const float4*)src)[i];
  ushort4 o;
  o.x = f2bf(v.x); o.y = f2bf(v.y); o.z = f2bf(v.z); o.w = f2bf(v.w);
  ((ushort4*)dst)[i] = o;
}

// ---------------------------------------------------------------------------
// K0: transpose+convert x[b][c][n] (f32) -> xT[b][n][c] (bf16), 64x64 tiles
// ---------------------------------------------------------------------------
__global__ __launch_bounds__(256) void k_transpose(const float* __restrict__ x,
                                                   u16* __restrict__ xT,
                                                   int nC, int nN) {
  __shared__ u16 tile[64 * 65];  // +1 u16 pad per row
  int b = blockIdx.z;
  int c0 = blockIdx.y * 64, n0 = blockIdx.x * 64;
  const float* xb = x + ((long)b * nC + c0) * nN + n0;
  u16* xTb = xT + ((long)b * nN + n0) * nC + c0;
  int tid = threadIdx.x;
#pragma unroll
  for (int p = 0; p < 2; ++p) {
    int u = tid + p * 256;
    int r = u >> 3, nc = (u & 7) * 8;
    const float4* srcp = (const float4*)(xb + (long)r * nN + nc);
    float4 v0 = srcp[0], v1 = srcp[1];
    int base = r * 65 + nc;
    tile[base + 0] = f2bf(v0.x); tile[base + 1] = f2bf(v0.y);
    tile[base + 2] = f2bf(v0.z); tile[base + 3] = f2bf(v0.w);
    tile[base + 4] = f2bf(v1.x); tile[base + 5] = f2bf(v1.y);
    tile[base + 6] = f2bf(v1.z); tile[base + 7] = f2bf(v1.w);
  }
  __syncthreads();
#pragma unroll
  for (int p = 0; p < 2; ++p) {
    int u = tid + p * 256;
    int nr = u >> 3, cc = (u & 7) * 8;
    __align__(16) u16 tmp[8];
#pragma unroll
    for (int j = 0; j < 8; ++j) tmp[j] = tile[(cc + j) * 65 + nr];
    *(uint4*)(xTb + (long)nr * nC + cc) = *(uint4*)(tmp);
  }
}

// ---------------------------------------------------------------------------
// gemm_bt: Out[M,N] = A[M,K] * B[Ncols,K]^T (+bias, relu), bf16 in, fp32 acc
// m97 structure: 128x128 tile, 4 waves, 16x16x32 bf16 MFMA, width-16
// global_load_lds staging (unconditional; OOB tile rows clamp to last valid
// row — duplicates discarded by epilogue guards).
// BIAS_MODE: 0 none, 1 row (bias1[row]), 2 col (select bias1/bias2 by nSplit).
// ---------------------------------------------------------------------------
template <bool OUT_F32, int BIAS_MODE, bool RELU>
__global__ __launch_bounds__(256) void k_gemm_bt(
    const u16* __restrict__ A, int lda, long aBS,
    const u16* __restrict__ B1, const u16* __restrict__ B2, int nSplit,
    int ldb, long bBS,
    void* __restrict__ Out, int ldo, long oBS,
    const float* __restrict__ bias1, const float* __restrict__ bias2,
    int M, int N, int K) {
  __shared__ __align__(16) u16 As[128 * 32];
  __shared__ __align__(16) u16 Bs[128 * 32];
  int bz = blockIdx.z;
  int m0 = blockIdx.y * 128, n0 = blockIdx.x * 128;
  const u16* Ablk = A + (long)bz * aBS + (long)m0 * lda;
  const u16* Bblk =
      ((n0 < nSplit) ? (B1 + (long)n0 * ldb) : (B2 + (long)(n0 - nSplit) * ldb)) +
      (long)bz * bBS;
  int tid = threadIdx.x;
  int lane = tid & 63;
  int lane16 = lane & 15, quad = lane >> 4;
  int wid = tid >> 6;
  int wm = wid >> 1, wn = wid & 1;

  int rA0 = (lane >> 2);
  int kk = (lane & 3) * 8;
  int mMax = M - 1 - m0, nMax = N - 1 - n0;

  floatx4 acc[4][4];
#pragma unroll
  for (int i = 0; i < 4; ++i)
#pragma unroll
    for (int j = 0; j < 4; ++j) acc[i][j] = (floatx4){0.f, 0.f, 0.f, 0.f};

  for (int k0 = 0; k0 < K; k0 += 32) {
    __syncthreads();
#pragma unroll
    for (int h = 0; h < 2; ++h) {
      int ch = wid * 2 + h;
      int r = ch * 16 + rA0;
      int ra = min(r, mMax);
      const u16* srcA = Ablk + (long)ra * lda + k0 + kk;
      __builtin_amdgcn_global_load_lds(
          (const __attribute__((address_space(1))) void*)srcA,
          (__attribute__((address_space(3))) void*)&As[ch * 512], 16, 0, 0);
      int rb = min(r, nMax);
      const u16* srcB = Bblk + (long)rb * ldb + k0 + kk;
      __builtin_amdgcn_global_load_lds(
          (const __attribute__((address_space(1))) void*)srcB,
          (__attribute__((address_space(3))) void*)&Bs[ch * 512], 16, 0, 0);
    }
    __syncthreads();
    short8 af[4], bfr[4];
#pragma unroll
    for (int t = 0; t < 4; ++t)
      af[t] = *(const short8*)&As[(wm * 64 + t * 16 + lane16) * 32 + quad * 8];
#pragma unroll
    for (int t = 0; t < 4; ++t)
      bfr[t] = *(const short8*)&Bs[(wn * 64 + t * 16 + lane16) * 32 + quad * 8];
#pragma unroll
    for (int i = 0; i < 4; ++i)
#pragma unroll
      for (int j = 0; j < 4; ++j)
        acc[i][j] = __builtin_amdgcn_mfma_f32_16x16x32_bf16(af[i], bfr[j],
                                                            acc[i][j], 0, 0, 0);
  }

  // epilogue: C/D layout col=lane&15, row=quad*4+reg  [m89-verified]
  const float* bcolPtr = bias1;
  int bofs = 0;
  if (BIAS_MODE == 2 && n0 >= nSplit) { bcolPtr = bias2; bofs = nSplit; }
#pragma unroll
  for (int i = 0; i < 4; ++i) {
    int rowb = m0 + wm * 64 + i * 16 + quad * 4;
#pragma unroll
    for (int j = 0; j < 4; ++j) {
      int col = n0 + wn * 64 + j * 16 + lane16;
      if (col >= N) continue;
      float bc = 0.f;
      if (BIAS_MODE == 2) bc = bcolPtr[col - bofs];
#pragma unroll
      for (int r = 0; r < 4; ++r) {
        int row = rowb + r;
        if (row >= M) continue;
        float v = acc[i][j][r];
        if (BIAS_MODE == 2) v += bc;
        if (BIAS_MODE == 1) v += bias1[row];
        if (RELU) v = fmaxf(v, 0.f);
        if (OUT_F32)
          ((float*)Out)[(long)bz * oBS + (long)row * ldo + col] = v;
        else
          ((u16*)Out)[(long)bz * oBS + (long)row * ldo + col] = f2bf(v);
      }
    }
  }
}

// ---------------------------------------------------------------------------
// K3: log-space Sinkhorn, one block per batch. scores bf16 [b][64][1024].
// ---------------------------------------------------------------------------
__global__ __launch_bounds__(1024) void k_sinkhorn(
    const u16* __restrict__ S, const float* __restrict__ alphaPtr,
    float lmu, float lmu_bin, float lnu, float norm, u16* __restrict__ P) {
  __shared__ float u_[65];
  __shared__ float v_[1024];
  int b = blockIdx.x, tid = threadIdx.x;
  const u16* Sb = S + (long)b * 65536;
  float alpha = *alphaPtr;
  v_[tid] = 0.f;
  __syncthreads();
  int wid = tid >> 6, lane = tid & 63;
  for (int it = 0; it < 3; ++it) {
    for (int i = wid; i < 65; i += 16) {   // u-pass: wave per row
      float vals[16];
      float mx = -3.4e38f;
#pragma unroll
      for (int s = 0; s < 16; ++s) {
        int j = lane + s * 64;
        float z = (i < 64 ? bf2f(Sb[i * 1024 + j]) : alpha) + v_[j];
        vals[s] = z;
        mx = fmaxf(mx, z);
      }
#pragma unroll
      for (int off = 32; off > 0; off >>= 1) mx = fmaxf(mx, __shfl_xor(mx, off));
      float sum = 0.f;
#pragma unroll
      for (int s = 0; s < 16; ++s) sum += __expf(vals[s] - mx);
#pragma unroll
      for (int off = 32; off > 0; off >>= 1) sum += __shfl_xor(sum, off);
      if (lane == 0) u_[i] = (i < 64 ? lmu : lmu_bin) - (mx + __logf(sum));
    }
    __syncthreads();
    {  // v-pass: thread per column, online LSE over m=65
      float mx = -3.4e38f, sum = 0.f;
      for (int i = 0; i < 65; ++i) {
        float z = (i < 64 ? bf2f(Sb[i * 1024 + tid]) : alpha) + u_[i];
        if (z > mx) { sum = sum * __expf(mx - z) + 1.f; mx = z; }
        else sum += __expf(z - mx);
      }
      v_[tid] = lnu - (mx + __logf(sum));
    }
    __syncthreads();
  }
  float vj = v_[tid];
  u16* Pb = P + (long)b * 65536;
  for (int i = 0; i < 64; ++i) {
    float z = bf2f(Sb[i * 1024 + tid]) + u_[i] + vj - norm;
    Pb[i * 1024 + tid] = f2bf(__expf(fminf(z, 1.0f)));  // z<=0 mathematically
  }
}

// ---------------------------------------------------------------------------
// K4: split-K agg partials. aggP[kc][b][128][64] = f[b,128,kslice] P[b,64,kslice]^T
// grid (KS=4, 1, 32); 128x64 tile, wave w owns rows [32w, 32w+32).
// ---------------------------------------------------------------------------
__global__ __launch_bounds__(256) void k_agg(const u16* __restrict__ f,
                                             const u16* __restrict__ P,
                                             float* __restrict__ aggP) {
  __shared__ __align__(16) u16 Fs[128 * 32];
  __shared__ __align__(16) u16 Ps[64 * 32];
  int bz = blockIdx.z, kc = blockIdx.x;
  const u16* Fb = f + (long)bz * 128 * 1024;
  const u16* Pb = P + (long)bz * 64 * 1024;
  int tid = threadIdx.x, wid = tid >> 6, lane = tid & 63;
  int lane16 = lane & 15, quad = lane >> 4;
  int rA0 = lane >> 2, kk = (lane & 3) * 8;

  floatx4 acc[2][4];
#pragma unroll
  for (int i = 0; i < 2; ++i)
#pragma unroll
    for (int j = 0; j < 4; ++j) acc[i][j] = (floatx4){0.f, 0.f, 0.f, 0.f};

  for (int k0 = kc * 256; k0 < kc * 256 + 256; k0 += 32) {
    __syncthreads();
#pragma unroll
    for (int h = 0; h < 2; ++h) {
      int ch = wid * 2 + h;
      int r = ch * 16 + rA0;
      const u16* srcF = Fb + (long)r * 1024 + k0 + kk;
      __builtin_amdgcn_global_load_lds(
          (const __attribute__((address_space(1))) void*)srcF,
          (__attribute__((address_space(3))) void*)&Fs[ch * 512], 16, 0, 0);
    }
    {
      int r = wid * 16 + rA0;
      const u16* srcP = Pb + (long)r * 1024 + k0 + kk;
      __builtin_amdgcn_global_load_lds(
          (const __attribute__((address_space(1))) void*)srcP,
          (__attribute__((address_space(3))) void*)&Ps[wid * 512], 16, 0, 0);
    }
    __syncthreads();
    short8 af[2], bfr[4];
#pragma unroll
    for (int t = 0; t < 2; ++t)
      af[t] = *(const short8*)&Fs[(wid * 32 + t * 16 + lane16) * 32 + quad * 8];
#pragma unroll
    for (int j = 0; j < 4; ++j)
      bfr[j] = *(const short8*)&Ps[(j * 16 + lane16) * 32 + quad * 8];
#pragma unroll
    for (int i = 0; i < 2; ++i)
#pragma unroll
      for (int j = 0; j < 4; ++j)
        acc[i][j] = __builtin_amdgcn_mfma_f32_16x16x32_bf16(af[i], bfr[j],
                                                            acc[i][j], 0, 0, 0);
  }
  float* ab = aggP + ((long)kc * 32 + bz) * 8192;
#pragma unroll
  for (int i = 0; i < 2; ++i)
#pragma unroll
    for (int j = 0; j < 4; ++j)
#pragma unroll
      for (int r = 0; r < 4; ++r) {
        int row = wid * 32 + i * 16 + quad * 4 + r;
        int col = j * 16 + lane16;
        ab[row * 64 + col] = acc[i][j][r];
      }
}

// ---------------------------------------------------------------------------
// token MLP, parallelized: k_mlp1 grid (8,32): 64 outputs/block, wave/row.
// ---------------------------------------------------------------------------
DEVINL float waveSum(float x) {
#pragma unroll
  for (int off = 32; off > 0; off >>= 1) x += __shfl_xor(x, off);
  return x;
}

__global__ __launch_bounds__(256) void k_mlp1(const float* __restrict__ t,
                                              const float* __restrict__ w1,
                                              const float* __restrict__ b1,
                                              float* __restrict__ h1) {
  __shared__ float tl[1536];
  int b = blockIdx.y, og = blockIdx.x;
  int tid = threadIdx.x, wid = tid >> 6, lane = tid & 63;
  for (int i = tid; i < 1536; i += 256) tl[i] = t[b * 1536 + i];
  __syncthreads();
#pragma unroll 4
  for (int oi = 0; oi < 16; ++oi) {
    int o = og * 64 + wid * 16 + oi;
    const float* wr = w1 + (long)o * 1536;
    float acc = 0.f;
#pragma unroll
    for (int s = 0; s < 24; ++s) { int c = lane + s * 64; acc += tl[c] * wr[c]; }
    acc = waveSum(acc);
    if (lane == 0) h1[b * 512 + o] = fmaxf(acc + b1[o], 0.f);
  }
}

__global__ __launch_bounds__(256) void k_mlp2(const float* __restrict__ h1,
                                              const float* __restrict__ w2,
                                              const float* __restrict__ b2,
                                              float* __restrict__ tk) {
  __shared__ float hl[512];
  int b = blockIdx.y, og = blockIdx.x;
  int tid = threadIdx.x, wid = tid >> 6, lane = tid & 63;
  for (int i = tid; i < 512; i += 256) hl[i] = h1[b * 512 + i];
  __syncthreads();
#pragma unroll 4
  for (int oi = 0; oi < 16; ++oi) {
    int o = og * 64 + wid * 16 + oi;
    const float* wr = w2 + (long)o * 512;
    float acc = 0.f;
#pragma unroll
    for (int s = 0; s < 8; ++s) { int c = lane + s * 64; acc += hl[c] * wr[c]; }
    acc = waveSum(acc);
    if (lane == 0) tk[b * 256 + o] = acc + b2[o];
  }
}

// ---------------------------------------------------------------------------
// K5: norms + output. Sums 4 agg partials into LDS, then all norms from LDS.
// ---------------------------------------------------------------------------
DEVINL float blockSum256(float x, float* red) {
#pragma unroll
  for (int off = 32; off > 0; off >>= 1) x += __shfl_xor(x, off);
  int wid = threadIdx.x >> 6;
  __syncthreads();
  if ((threadIdx.x & 63) == 0) red[wid] = x;
  __syncthreads();
  return red[0] + red[1] + red[2] + red[3];
}

__global__ __launch_bounds__(256) void k_norms(const float* __restrict__ tk,
                                               const float* __restrict__ aggP,
                                               float* __restrict__ out) {
  __shared__ float asum[8192];
  __shared__ float cn[64];
  __shared__ float red[4];
  int b = blockIdx.x, tid = threadIdx.x;
  const float* a0 = aggP + (long)b * 8192;
  for (int idx = tid; idx < 8192; idx += 256)
    asum[idx] = a0[idx] + a0[32 * 8192 + idx] + a0[64 * 8192 + idx] +
                a0[96 * 8192 + idx];
  __syncthreads();
  float tkv = tk[b * 256 + tid];
  float tss = blockSum256(tkv * tkv, red);
  float tn = fmaxf(sqrtf(tss), 1e-12f);
  if (tid < 64) {
    float s = 0.f;
    for (int l = 0; l < 128; ++l) { float a = asum[l * 64 + tid]; s += a * a; }
    cn[tid] = fmaxf(sqrtf(s), 1e-12f);
  }
  __syncthreads();
  float gs = (tkv / tn) * (tkv / tn);
  for (int idx = tid; idx < 8192; idx += 256) {
    float a = asum[idx] / cn[idx & 63];
    gs += a * a;
  }
  float G = blockSum256(gs, red);
  float inv = 1.f / fmaxf(sqrtf(G), 1e-12f);
  float* ob = out + (long)b * 8448;
  ob[tid] = tkv / tn * inv;
  for (int idx = tid; idx < 8192; idx += 256)
    ob[256 + idx] = asum[idx] / cn[idx & 63] * inv;
}

// ---------------------------------------------------------------------------
extern "C" void kernel_launch(void* const* d_in, const int* in_sizes, int n_in,
                              void* d_out, int out_size, void* d_ws,
                              size_t ws_size, hipStream_t stream) {
  const float* x = (const float*)d_in[0];
  const float* t = (const float*)d_in[1];
  const float* cf_w1 = (const float*)d_in[2];
  const float* cf_b1 = (const float*)d_in[3];
  const float* cf_w2 = (const float*)d_in[4];
  const float* cf_b2 = (const float*)d_in[5];
  const float* sc_w1 = (const float*)d_in[6];
  const float* sc_b1 = (const float*)d_in[7];
  const float* sc_w2 = (const float*)d_in[8];
  const float* sc_b2 = (const float*)d_in[9];
  const float* tk_w1 = (const float*)d_in[10];
  const float* tk_b1 = (const float*)d_in[11];
  const float* tk_w2 = (const float*)d_in[12];
  const float* tk_b2 = (const float*)d_in[13];
  const float* dust = (const float*)d_in[14];
  float* out = (float*)d_out;

  // workspace layout (all 16B-multiples)
  char* ws = (char*)d_ws;
  size_t off = 0;
  u16* wc1 = (u16*)(ws + off); off += (size_t)512 * 1536 * 2;        // cf_w1 bf16
  u16* ws1 = (u16*)(ws + off); off += (size_t)512 * 1536 * 2;        // sc_w1 bf16
  u16* wc2 = (u16*)(ws + off); off += (size_t)128 * 512 * 2;         // cf_w2 bf16
  u16* ws2 = (u16*)(ws + off); off += (size_t)64 * 512 * 2;          // sc_w2 bf16
  u16* f = (u16*)(ws + off);   off += (size_t)32 * 128 * 1024 * 2;   // 8 MB
  u16* scr = (u16*)(ws + off); off += (size_t)32 * 64 * 1024 * 2;    // 4 MB
  u16* P = (u16*)(ws + off);   off += (size_t)32 * 64 * 1024 * 2;    // 4 MB
  float* aggP = (float*)(ws + off); off += (size_t)4 * 32 * 128 * 64 * 4; // 4 MB
  float* h1ws = (float*)(ws + off); off += (size_t)32 * 512 * 4;     // 64 KB
  float* tkws = (float*)(ws + off); off += (size_t)32 * 256 * 4;     // 32 KB
  size_t fixed = off;
  size_t perB = (size_t)1024 * 1536 * 2 + (size_t)1024 * 1024 * 2;   // xT+hT
  int c = 1;
  const int cands[6] = {32, 16, 8, 4, 2, 1};
  for (int k = 0; k < 6; ++k)
    if (fixed + (size_t)cands[k] * perB <= ws_size) { c = cands[k]; break; }
  u16* xT = (u16*)(ws + fixed);
  u16* hT = (u16*)(ws + fixed + (size_t)c * 1024 * 1536 * 2);

  // convert weights to bf16
  k_cvt<<<768, 256, 0, stream>>>(cf_w1, wc1, 512 * 1536 / 4);
  k_cvt<<<768, 256, 0, stream>>>(sc_w1, ws1, 512 * 1536 / 4);
  k_cvt<<<64, 256, 0, stream>>>(cf_w2, wc2, 128 * 512 / 4);
  k_cvt<<<32, 256, 0, stream>>>(sc_w2, ws2, 64 * 512 / 4);

  // token MLP (independent of the conv path — launch early)
  k_mlp1<<<dim3(8, 32), 256, 0, stream>>>(t, tk_w1, tk_b1, h1ws);
  k_mlp2<<<dim3(4, 32), 256, 0, stream>>>(h1ws, tk_w2, tk_b2, tkws);

  float norm = -logf(1088.f);          // -log(m+n), m=64 n=1024
  float lmu = norm;
  float lmu_bin = logf(960.f) + norm;  // log(n-m) + norm
  float lnu = norm;

  for (int cb = 0; cb < 32; cb += c) {
    // K0: x[b][c][n] f32 -> xT[b][n][c] bf16
    k_transpose<<<dim3(16, 24, c), 256, 0, stream>>>(
        x + (size_t)cb * 1536 * 1024, xT, 1536, 1024);
    // K1: hT[b][n][o] = relu(xT . W1^T + b1), fused cf(o<512) + sc(o>=512)
    k_gemm_bt<false, 2, true><<<dim3(8, 8, c), 256, 0, stream>>>(
        xT, 1536, (long)1024 * 1536,
        wc1, ws1, 512, 1536, 0,
        hT, 1024, (long)1024 * 1024,
        cf_b1, sc_b1, 1024, 1024, 1536);
    // K2a: f[b][l][n] = cf_w2 . hT_cf^T + cf_b2   (bf16 out)
    k_gemm_bt<false, 1, false><<<dim3(8, 1, c), 256, 0, stream>>>(
        wc2, 512, 0,
        hT, hT, 1 << 30, 1024, (long)1024 * 1024,
        f + (size_t)cb * 128 * 1024, 1024, (long)128 * 1024,
        cf_b2, cf_b2, 128, 1024, 512);
    // K2b: scores[b][m][n] = sc_w2 . hT_sc^T + sc_b2   (bf16 out)
    k_gemm_bt<false, 1, false><<<dim3(8, 1, c), 256, 0, stream>>>(
        ws2, 512, 0,
        hT + 512, hT + 512, 1 << 30, 1024, (long)1024 * 1024,
        scr + (size_t)cb * 64 * 1024, 1024, (long)64 * 1024,
        sc_b2, sc_b2, 64, 1024, 512);
  }
  // K3: Sinkhorn -> P bf16 [b][64][1024]
  k_sinkhorn<<<32, 1024, 0, stream>>>(scr, dust, lmu, lmu_bin, lnu, norm, P);
  // K4: split-K agg partials [4][32][128][64]
  k_agg<<<dim3(4, 1, 32), 256, 0, stream>>>(f, P, aggP);
  // K5: norms + output
  k_norms<<<32, 256, 0, stream>>>(tkws, aggP, out);
}

// Round 6
// 638.598 us; speedup vs baseline: 1.4334x; 1.0643x over previous
//
#include <hip/hip_runtime.h>
#include <hip/hip_bf16.h>
#include <math.h>

typedef unsigned short u16;
typedef __attribute__((ext_vector_type(8))) short short8;
typedef __attribute__((ext_vector_type(4))) float floatx4;

#define DEVINL __device__ __forceinline__

DEVINL float bf2f(u16 u) { union { unsigned int i; float f; } v; v.i = ((unsigned int)u) << 16; return v.f; }
DEVINL u16 f2bf(float f) {
  union { unsigned int i; float f; } v; v.f = f;
  unsigned int i = v.i;
  unsigned int r = (i + 0x7fffu + ((i >> 16) & 1u)) >> 16;
  return (u16)r;
}

// ---------------------------------------------------------------------------
// cvt: f32 -> bf16 elementwise. n4 = elems/4.
// ---------------------------------------------------------------------------
__global__ __launch_bounds__(256) void k_cvt(const float* __restrict__ src,
                                             u16* __restrict__ dst, int n4) {
  int i = blockIdx.x * 256 + threadIdx.x;
  if (i >= n4) return;
  float4 v = ((const float4*)src)[i];
  ushort4 o;
  o.x = f2bf(v.x); o.y = f2bf(v.y); o.z = f2bf(v.z); o.w = f2bf(v.w);
  ((ushort4*)dst)[i] = o;
}

// sc_w2 [64][512] f32 -> padded [128][512] bf16 (rows 64.. = 0)
__global__ __launch_bounds__(256) void k_pad_scw2(const float* __restrict__ src,
                                                  u16* __restrict__ dst) {
  int i = blockIdx.x * 256 + threadIdx.x;  // 16384 float4-elems
  int r = i >> 7;
  ushort4 o = {0, 0, 0, 0};
  if (r < 64) {
    float4 v = ((const float4*)src)[i];
    o.x = f2bf(v.x); o.y = f2bf(v.y); o.z = f2bf(v.z); o.w = f2bf(v.w);
  }
  ((ushort4*)dst)[i] = o;
}

__global__ void k_pad_scb2(const float* __restrict__ src, float* __restrict__ dst) {
  int i = threadIdx.x;  // 128
  dst[i] = (i < 64) ? src[i] : 0.f;
}

// ---------------------------------------------------------------------------
// K0: transpose+convert x[b][c][n] (f32) -> xT[b][n][c] (bf16), 64x64 tiles
// ---------------------------------------------------------------------------
__global__ __launch_bounds__(256) void k_transpose(const float* __restrict__ x,
                                                   u16* __restrict__ xT,
                                                   int nC, int nN) {
  __shared__ u16 tile[64 * 65];
  int b = blockIdx.z;
  int c0 = blockIdx.y * 64, n0 = blockIdx.x * 64;
  const float* xb = x + ((long)b * nC + c0) * nN + n0;
  u16* xTb = xT + ((long)b * nN + n0) * nC + c0;
  int tid = threadIdx.x;
#pragma unroll
  for (int p = 0; p < 2; ++p) {
    int u = tid + p * 256;
    int r = u >> 3, nc = (u & 7) * 8;
    const float4* srcp = (const float4*)(xb + (long)r * nN + nc);
    float4 v0 = srcp[0], v1 = srcp[1];
    int base = r * 65 + nc;
    tile[base + 0] = f2bf(v0.x); tile[base + 1] = f2bf(v0.y);
    tile[base + 2] = f2bf(v0.z); tile[base + 3] = f2bf(v0.w);
    tile[base + 4] = f2bf(v1.x); tile[base + 5] = f2bf(v1.y);
    tile[base + 6] = f2bf(v1.z); tile[base + 7] = f2bf(v1.w);
  }
  __syncthreads();
#pragma unroll
  for (int p = 0; p < 2; ++p) {
    int u = tid + p * 256;
    int nr = u >> 3, cc = (u & 7) * 8;
    __align__(16) u16 tmp[8];
#pragma unroll
    for (int j = 0; j < 8; ++j) tmp[j] = tile[(cc + j) * 65 + nr];
    *(uint4*)(xTb + (long)nr * nC + cc) = *(uint4*)(tmp);
  }
}

// ---------------------------------------------------------------------------
// gemm64: Out[M,N] = A[M,K] * B[Ncols,K]^T (+bias, relu), bf16 in, fp32 acc.
// FULL TILES ONLY: M,N % 128 == 0, K % 64 == 0. BK=64 (32 MFMA per barrier
// round), width-16 global_load_lds staging with XOR k-piece swizzle:
//   staging lane loads global piece (lane&7)^(lane>>3) -> LDS slot (lane&7);
//   LDS slot s of row r holds global piece s^(r&7); fragment ds_read_b128 at
//   slot (h*4+quad)^(row&7) -> banks fully spread (2-way = free, m136).
// BIAS_MODE: 0 none, 1 row (bias1[row]), 2 col (bias1/bias2 split at nSplit).
// ---------------------------------------------------------------------------
template <bool OUT_F32, int BIAS_MODE, bool RELU>
__global__ __launch_bounds__(256) void k_gemm64(
    const u16* __restrict__ A, int lda, long aBS,
    const u16* __restrict__ B1, const u16* __restrict__ B2, int nSplit,
    int ldb, long bBS,
    void* __restrict__ Out, int ldo, long oBS,
    const float* __restrict__ bias1, const float* __restrict__ bias2,
    int M, int N, int K) {
  __shared__ __align__(16) u16 As[128 * 64];  // 16 KB
  __shared__ __align__(16) u16 Bs[128 * 64];  // 16 KB
  int bz = blockIdx.z;
  int m0 = blockIdx.y * 128, n0 = blockIdx.x * 128;
  const u16* Ablk = A + (long)bz * aBS + (long)m0 * lda;
  const u16* Bblk =
      ((n0 < nSplit) ? (B1 + (long)n0 * ldb) : (B2 + (long)(n0 - nSplit) * ldb)) +
      (long)bz * bBS;
  int tid = threadIdx.x;
  int lane = tid & 63;
  int lane16 = lane & 15, quad = lane >> 4;
  int wid = tid >> 6;
  int wm = wid >> 1, wn = wid & 1;

  // staging geometry: chunk ch = 8 rows x 64 u16 = 1KB; wave stages chunks
  // 4w..4w+3 of both As and Bs. lane -> row ch*8 + (lane>>3), swizzled piece.
  int rIn = lane >> 3;
  int kkSw = ((lane & 7) ^ rIn) * 8;

  floatx4 acc[4][4];
#pragma unroll
  for (int i = 0; i < 4; ++i)
#pragma unroll
    for (int j = 0; j < 4; ++j) acc[i][j] = (floatx4){0.f, 0.f, 0.f, 0.f};

  for (int k0 = 0; k0 < K; k0 += 64) {
    __syncthreads();
#pragma unroll
    for (int h = 0; h < 4; ++h) {
      int ch = wid * 4 + h;
      int r = ch * 8 + rIn;
      const u16* srcA = Ablk + (long)r * lda + k0 + kkSw;
      __builtin_amdgcn_global_load_lds(
          (const __attribute__((address_space(1))) void*)srcA,
          (__attribute__((address_space(3))) void*)&As[ch * 512], 16, 0, 0);
      const u16* srcB = Bblk + (long)r * ldb + k0 + kkSw;
      __builtin_amdgcn_global_load_lds(
          (const __attribute__((address_space(1))) void*)srcB,
          (__attribute__((address_space(3))) void*)&Bs[ch * 512], 16, 0, 0);
    }
    __syncthreads();
#pragma unroll
    for (int h2 = 0; h2 < 2; ++h2) {
      short8 af[4], bfr[4];
#pragma unroll
      for (int t = 0; t < 4; ++t) {
        int ra = wm * 64 + t * 16 + lane16;
        af[t] = *(const short8*)&As[ra * 64 + (((h2 * 4 + quad) ^ (ra & 7)) * 8)];
      }
#pragma unroll
      for (int t = 0; t < 4; ++t) {
        int rb = wn * 64 + t * 16 + lane16;
        bfr[t] = *(const short8*)&Bs[rb * 64 + (((h2 * 4 + quad) ^ (rb & 7)) * 8)];
      }
#pragma unroll
      for (int i = 0; i < 4; ++i)
#pragma unroll
        for (int j = 0; j < 4; ++j)
          acc[i][j] = __builtin_amdgcn_mfma_f32_16x16x32_bf16(af[i], bfr[j],
                                                              acc[i][j], 0, 0, 0);
    }
  }

  // epilogue: C/D layout col=lane&15, row=quad*4+reg  [m89-verified]
  const float* bcolPtr = bias1;
  int bofs = 0;
  if (BIAS_MODE == 2 && n0 >= nSplit) { bcolPtr = bias2; bofs = nSplit; }
#pragma unroll
  for (int i = 0; i < 4; ++i) {
    int rowb = m0 + wm * 64 + i * 16 + quad * 4;
#pragma unroll
    for (int j = 0; j < 4; ++j) {
      int col = n0 + wn * 64 + j * 16 + lane16;
      float bc = 0.f;
      if (BIAS_MODE == 2) bc = bcolPtr[col - bofs];
#pragma unroll
      for (int r = 0; r < 4; ++r) {
        int row = rowb + r;
        float v = acc[i][j][r];
        if (BIAS_MODE == 2) v += bc;
        if (BIAS_MODE == 1) v += bias1[row];
        if (RELU) v = fmaxf(v, 0.f);
        if (OUT_F32)
          ((float*)Out)[(long)bz * oBS + (long)row * ldo + col] = v;
        else
          ((u16*)Out)[(long)bz * oBS + (long)row * ldo + col] = f2bf(v);
      }
    }
  }
}

// ---------------------------------------------------------------------------
// K3: log-space Sinkhorn, one block per batch. scores bf16, 128-row stride
// (rows 0..63 valid). v-pass = two-pass LSE (independent pipelined loads).
// ---------------------------------------------------------------------------
__global__ __launch_bounds__(1024) void k_sinkhorn(
    const u16* __restrict__ S, const float* __restrict__ alphaPtr,
    float lmu, float lmu_bin, float lnu, float norm, u16* __restrict__ P) {
  __shared__ float u_[65];
  __shared__ float v_[1024];
  int b = blockIdx.x, tid = threadIdx.x;
  const u16* Sb = S + (long)b * 131072;
  float alpha = *alphaPtr;
  v_[tid] = 0.f;
  __syncthreads();
  int wid = tid >> 6, lane = tid & 63;
  for (int it = 0; it < 3; ++it) {
    for (int i = wid; i < 65; i += 16) {   // u-pass: wave per row
      float vals[16];
      float mx = -3.4e38f;
#pragma unroll
      for (int s = 0; s < 16; ++s) {
        int j = lane + s * 64;
        float z = (i < 64 ? bf2f(Sb[i * 1024 + j]) : alpha) + v_[j];
        vals[s] = z;
        mx = fmaxf(mx, z);
      }
#pragma unroll
      for (int off = 32; off > 0; off >>= 1) mx = fmaxf(mx, __shfl_xor(mx, off));
      float sum = 0.f;
#pragma unroll
      for (int s = 0; s < 16; ++s) sum += __expf(vals[s] - mx);
#pragma unroll
      for (int off = 32; off > 0; off >>= 1) sum += __shfl_xor(sum, off);
      if (lane == 0) u_[i] = (i < 64 ? lmu : lmu_bin) - (mx + __logf(sum));
    }
    __syncthreads();
    {  // v-pass: thread per column, two-pass LSE over m=65
      float mx = alpha + u_[64];
#pragma unroll 8
      for (int i = 0; i < 64; ++i)
        mx = fmaxf(mx, bf2f(Sb[i * 1024 + tid]) + u_[i]);
      float sum = __expf(alpha + u_[64] - mx);
#pragma unroll 8
      for (int i = 0; i < 64; ++i)
        sum += __expf(bf2f(Sb[i * 1024 + tid]) + u_[i] - mx);
      v_[tid] = lnu - (mx + __logf(sum));
    }
    __syncthreads();
  }
  float vj = v_[tid];
  u16* Pb = P + (long)b * 65536;
#pragma unroll 8
  for (int i = 0; i < 64; ++i) {
    float z = bf2f(Sb[i * 1024 + tid]) + u_[i] + vj - norm;
    Pb[i * 1024 + tid] = f2bf(__expf(fminf(z, 1.0f)));  // z<=0 mathematically
  }
}

// ---------------------------------------------------------------------------
// K4: split-K agg partials. aggP[kc][b][128][64] = f[b,128,ks] P[b,64,ks]^T
// ---------------------------------------------------------------------------
__global__ __launch_bounds__(256) void k_agg(const u16* __restrict__ f,
                                             const u16* __restrict__ P,
                                             float* __restrict__ aggP) {
  __shared__ __align__(16) u16 Fs[128 * 32];
  __shared__ __align__(16) u16 Ps[64 * 32];
  int bz = blockIdx.z, kc = blockIdx.x;
  const u16* Fb = f + (long)bz * 128 * 1024;
  const u16* Pb = P + (long)bz * 64 * 1024;
  int tid = threadIdx.x, wid = tid >> 6, lane = tid & 63;
  int lane16 = lane & 15, quad = lane >> 4;
  int rA0 = lane >> 2, kk = (lane & 3) * 8;

  floatx4 acc[2][4];
#pragma unroll
  for (int i = 0; i < 2; ++i)
#pragma unroll
    for (int j = 0; j < 4; ++j) acc[i][j] = (floatx4){0.f, 0.f, 0.f, 0.f};

  for (int k0 = kc * 256; k0 < kc * 256 + 256; k0 += 32) {
    __syncthreads();
#pragma unroll
    for (int h = 0; h < 2; ++h) {
      int ch = wid * 2 + h;
      int r = ch * 16 + rA0;
      const u16* srcF = Fb + (long)r * 1024 + k0 + kk;
      __builtin_amdgcn_global_load_lds(
          (const __attribute__((address_space(1))) void*)srcF,
          (__attribute__((address_space(3))) void*)&Fs[ch * 512], 16, 0, 0);
    }
    {
      int r = wid * 16 + rA0;
      const u16* srcP = Pb + (long)r * 1024 + k0 + kk;
      __builtin_amdgcn_global_load_lds(
          (const __attribute__((address_space(1))) void*)srcP,
          (__attribute__((address_space(3))) void*)&Ps[wid * 512], 16, 0, 0);
    }
    __syncthreads();
    short8 af[2], bfr[4];
#pragma unroll
    for (int t = 0; t < 2; ++t)
      af[t] = *(const short8*)&Fs[(wid * 32 + t * 16 + lane16) * 32 + quad * 8];
#pragma unroll
    for (int j = 0; j < 4; ++j)
      bfr[j] = *(const short8*)&Ps[(j * 16 + lane16) * 32 + quad * 8];
#pragma unroll
    for (int i = 0; i < 2; ++i)
#pragma unroll
      for (int j = 0; j < 4; ++j)
        acc[i][j] = __builtin_amdgcn_mfma_f32_16x16x32_bf16(af[i], bfr[j],
                                                            acc[i][j], 0, 0, 0);
  }
  float* ab = aggP + ((long)kc * 32 + bz) * 8192;
#pragma unroll
  for (int i = 0; i < 2; ++i)
#pragma unroll
    for (int j = 0; j < 4; ++j)
#pragma unroll
      for (int r = 0; r < 4; ++r) {
        int row = wid * 32 + i * 16 + quad * 4 + r;
        int col = j * 16 + lane16;
        ab[row * 64 + col] = acc[i][j][r];
      }
}

// ---------------------------------------------------------------------------
// token MLP, parallelized.
// ---------------------------------------------------------------------------
DEVINL float waveSum(float x) {
#pragma unroll
  for (int off = 32; off > 0; off >>= 1) x += __shfl_xor(x, off);
  return x;
}

__global__ __launch_bounds__(256) void k_mlp1(const float* __restrict__ t,
                                              const float* __restrict__ w1,
                                              const float* __restrict__ b1,
                                              float* __restrict__ h1) {
  __shared__ float tl[1536];
  int b = blockIdx.y, og = blockIdx.x;
  int tid = threadIdx.x, wid = tid >> 6, lane = tid & 63;
  for (int i = tid; i < 1536; i += 256) tl[i] = t[b * 1536 + i];
  __syncthreads();
#pragma unroll 4
  for (int oi = 0; oi < 16; ++oi) {
    int o = og * 64 + wid * 16 + oi;
    const float* wr = w1 + (long)o * 1536;
    float acc = 0.f;
#pragma unroll
    for (int s = 0; s < 24; ++s) { int c = lane + s * 64; acc += tl[c] * wr[c]; }
    acc = waveSum(acc);
    if (lane == 0) h1[b * 512 + o] = fmaxf(acc + b1[o], 0.f);
  }
}

__global__ __launch_bounds__(256) void k_mlp2(const float* __restrict__ h1,
                                              const float* __restrict__ w2,
                                              const float* __restrict__ b2,
                                              float* __restrict__ tk) {
  __shared__ float hl[512];
  int b = blockIdx.y, og = blockIdx.x;
  int tid = threadIdx.x, wid = tid >> 6, lane = tid & 63;
  for (int i = tid; i < 512; i += 256) hl[i] = h1[b * 512 + i];
  __syncthreads();
#pragma unroll 4
  for (int oi = 0; oi < 16; ++oi) {
    int o = og * 64 + wid * 16 + oi;
    const float* wr = w2 + (long)o * 512;
    float acc = 0.f;
#pragma unroll
    for (int s = 0; s < 8; ++s) { int c = lane + s * 64; acc += hl[c] * wr[c]; }
    acc = waveSum(acc);
    if (lane == 0) tk[b * 256 + o] = acc + b2[o];
  }
}

// ---------------------------------------------------------------------------
// K5: norms + output.
// ---------------------------------------------------------------------------
DEVINL float blockSum256(float x, float* red) {
#pragma unroll
  for (int off = 32; off > 0; off >>= 1) x += __shfl_xor(x, off);
  int wid = threadIdx.x >> 6;
  __syncthreads();
  if ((threadIdx.x & 63) == 0) red[wid] = x;
  __syncthreads();
  return red[0] + red[1] + red[2] + red[3];
}

__global__ __launch_bounds__(256) void k_norms(const float* __restrict__ tk,
                                               const float* __restrict__ aggP,
                                               float* __restrict__ out) {
  __shared__ float asum[8192];
  __shared__ float cn[64];
  __shared__ float red[4];
  int b = blockIdx.x, tid = threadIdx.x;
  const float* a0 = aggP + (long)b * 8192;
  for (int idx = tid; idx < 8192; idx += 256)
    asum[idx] = a0[idx] + a0[32 * 8192 + idx] + a0[64 * 8192 + idx] +
                a0[96 * 8192 + idx];
  __syncthreads();
  float tkv = tk[b * 256 + tid];
  float tss = blockSum256(tkv * tkv, red);
  float tn = fmaxf(sqrtf(tss), 1e-12f);
  if (tid < 64) {
    float s = 0.f;
    for (int l = 0; l < 128; ++l) { float a = asum[l * 64 + tid]; s += a * a; }
    cn[tid] = fmaxf(sqrtf(s), 1e-12f);
  }
  __syncthreads();
  float gs = (tkv / tn) * (tkv / tn);
  for (int idx = tid; idx < 8192; idx += 256) {
    float a = asum[idx] / cn[idx & 63];
    gs += a * a;
  }
  float G = blockSum256(gs, red);
  float inv = 1.f / fmaxf(sqrtf(G), 1e-12f);
  float* ob = out + (long)b * 8448;
  ob[tid] = tkv / tn * inv;
  for (int idx = tid; idx < 8192; idx += 256)
    ob[256 + idx] = asum[idx] / cn[idx & 63] * inv;
}

// ---------------------------------------------------------------------------
extern "C" void kernel_launch(void* const* d_in, const int* in_sizes, int n_in,
                              void* d_out, int out_size, void* d_ws,
                              size_t ws_size, hipStream_t stream) {
  const float* x = (const float*)d_in[0];
  const float* t = (const float*)d_in[1];
  const float* cf_w1 = (const float*)d_in[2];
  const float* cf_b1 = (const float*)d_in[3];
  const float* cf_w2 = (const float*)d_in[4];
  const float* cf_b2 = (const float*)d_in[5];
  const float* sc_w1 = (const float*)d_in[6];
  const float* sc_b1 = (const float*)d_in[7];
  const float* sc_w2 = (const float*)d_in[8];
  const float* sc_b2 = (const float*)d_in[9];
  const float* tk_w1 = (const float*)d_in[10];
  const float* tk_b1 = (const float*)d_in[11];
  const float* tk_w2 = (const float*)d_in[12];
  const float* tk_b2 = (const float*)d_in[13];
  const float* dust = (const float*)d_in[14];
  float* out = (float*)d_out;

  // workspace layout (all 16B-multiples)
  char* ws = (char*)d_ws;
  size_t off = 0;
  u16* wc1 = (u16*)(ws + off); off += (size_t)512 * 1536 * 2;        // cf_w1 bf16
  u16* ws1 = (u16*)(ws + off); off += (size_t)512 * 1536 * 2;        // sc_w1 bf16
  u16* wc2 = (u16*)(ws + off); off += (size_t)128 * 512 * 2;         // cf_w2 bf16
  u16* ws2p = (u16*)(ws + off); off += (size_t)128 * 512 * 2;        // sc_w2 padded
  float* scb2p = (float*)(ws + off); off += (size_t)128 * 4;         // sc_b2 padded
  u16* f = (u16*)(ws + off);   off += (size_t)32 * 128 * 1024 * 2;   // 8 MB
  u16* scr = (u16*)(ws + off); off += (size_t)32 * 128 * 1024 * 2;   // 8 MB (128-row stride)
  u16* P = (u16*)(ws + off);   off += (size_t)32 * 64 * 1024 * 2;    // 4 MB
  float* aggP = (float*)(ws + off); off += (size_t)4 * 32 * 128 * 64 * 4; // 4 MB
  float* h1ws = (float*)(ws + off); off += (size_t)32 * 512 * 4;     // 64 KB
  float* tkws = (float*)(ws + off); off += (size_t)32 * 256 * 4;     // 32 KB
  size_t fixed = off;
  size_t perB = (size_t)1024 * 1536 * 2 + (size_t)1024 * 1024 * 2;   // xT+hT
  int c = 1;
  const int cands[6] = {32, 16, 8, 4, 2, 1};
  for (int k = 0; k < 6; ++k)
    if (fixed + (size_t)cands[k] * perB <= ws_size) { c = cands[k]; break; }
  u16* xT = (u16*)(ws + fixed);
  u16* hT = (u16*)(ws + fixed + (size_t)c * 1024 * 1536 * 2);

  // weight conversion / packing
  k_cvt<<<768, 256, 0, stream>>>(cf_w1, wc1, 512 * 1536 / 4);
  k_cvt<<<768, 256, 0, stream>>>(sc_w1, ws1, 512 * 1536 / 4);
  k_cvt<<<64, 256, 0, stream>>>(cf_w2, wc2, 128 * 512 / 4);
  k_pad_scw2<<<64, 256, 0, stream>>>(sc_w2, ws2p);
  k_pad_scb2<<<1, 128, 0, stream>>>(sc_b2, scb2p);

  // token MLP (independent of the conv path — launch early)
  k_mlp1<<<dim3(8, 32), 256, 0, stream>>>(t, tk_w1, tk_b1, h1ws);
  k_mlp2<<<dim3(4, 32), 256, 0, stream>>>(h1ws, tk_w2, tk_b2, tkws);

  float norm = -logf(1088.f);          // -log(m+n), m=64 n=1024
  float lmu = norm;
  float lmu_bin = logf(960.f) + norm;  // log(n-m) + norm
  float lnu = norm;

  for (int cb = 0; cb < 32; cb += c) {
    // K0: x[b][c][n] f32 -> xT[b][n][c] bf16
    k_transpose<<<dim3(16, 24, c), 256, 0, stream>>>(
        x + (size_t)cb * 1536 * 1024, xT, 1536, 1024);
    // K1: hT[b][n][o] = relu(xT . W1^T + b1), fused cf(o<512) + sc(o>=512)
    k_gemm64<false, 2, true><<<dim3(8, 8, c), 256, 0, stream>>>(
        xT, 1536, (long)1024 * 1536,
        wc1, ws1, 512, 1536, 0,
        hT, 1024, (long)1024 * 1024,
        cf_b1, sc_b1, 1024, 1024, 1536);
    // K2a: f[b][l][n] = cf_w2 . hT_cf^T + cf_b2   (bf16 out)
    k_gemm64<false, 1, false><<<dim3(8, 1, c), 256, 0, stream>>>(
        wc2, 512, 0,
        hT, hT, 1 << 30, 1024, (long)1024 * 1024,
        f + (size_t)cb * 128 * 1024, 1024, (long)128 * 1024,
        cf_b2, cf_b2, 128, 1024, 512);
    // K2b: scores (padded 128 rows, rows 0..63 valid) = sc_w2p . hT_sc^T
    k_gemm64<false, 1, false><<<dim3(8, 1, c), 256, 0, stream>>>(
        ws2p, 512, 0,
        hT + 512, hT + 512, 1 << 30, 1024, (long)1024 * 1024,
        scr + (size_t)cb * 128 * 1024, 1024, (long)128 * 1024,
        scb2p, scb2p, 128, 1024, 512);
  }
  // K3: Sinkhorn -> P bf16 [b][64][1024]
  k_sinkhorn<<<32, 1024, 0, stream>>>(scr, dust, lmu, lmu_bin, lnu, norm, P);
  // K4: split-K agg partials [4][32][128][64]
  k_agg<<<dim3(4, 1, 32), 256, 0, stream>>>(f, P, aggP);
  // K5: norms + output
  k_norms<<<32, 256, 0, stream>>>(tkws, aggP, out);
}

// Round 7
// 598.191 us; speedup vs baseline: 1.5302x; 1.0675x over previous
//
#include <hip/hip_runtime.h>
#include <hip/hip_bf16.h>
#include <math.h>

typedef unsigned short u16;
typedef __attribute__((ext_vector_type(8))) short short8;
typedef __attribute__((ext_vector_type(4))) float floatx4;

#define DEVINL __device__ __forceinline__

DEVINL float bf2f(u16 u) { union { unsigned int i; float f; } v; v.i = ((unsigned int)u) << 16; return v.f; }
DEVINL u16 f2bf(float f) {
  union { unsigned int i; float f; } v; v.f = f;
  unsigned int i = v.i;
  unsigned int r = (i + 0x7fffu + ((i >> 16) & 1u)) >> 16;
  return (u16)r;
}

// ---------------------------------------------------------------------------
// k_prep: all weight conversions in ONE dispatch. grid (768, 5).
//  y=0: cf_w1 f32->bf16 (196608 f4)   y=1: sc_w1 (196608 f4)
//  y=2: cf_w2 (16384 f4)              y=3: sc_w2 pad 64->128 rows (16384 f4)
//  y=4: sc_b2 pad (128 floats)
// ---------------------------------------------------------------------------
__global__ __launch_bounds__(256) void k_prep(
    const float* __restrict__ cf_w1, u16* __restrict__ wc1,
    const float* __restrict__ sc_w1, u16* __restrict__ ws1,
    const float* __restrict__ cf_w2, u16* __restrict__ wc2,
    const float* __restrict__ sc_w2, u16* __restrict__ ws2p,
    const float* __restrict__ sc_b2, float* __restrict__ scb2p) {
  int i = blockIdx.x * 256 + threadIdx.x;
  int job = blockIdx.y;
  if (job == 4) {
    if (i < 128) scb2p[i] = (i < 64) ? sc_b2[i] : 0.f;
    return;
  }
  const float* src = (job == 0) ? cf_w1 : (job == 1) ? sc_w1 : (job == 2) ? cf_w2 : sc_w2;
  u16* dst = (job == 0) ? wc1 : (job == 1) ? ws1 : (job == 2) ? wc2 : ws2p;
  int n4 = (job <= 1) ? 196608 : 16384;
  if (i >= n4) return;
  ushort4 o = {0, 0, 0, 0};
  if (job != 3 || (i >> 7) < 64) {  // job 3: rows >= 64 stay zero
    float4 v = ((const float4*)src)[i];
    o.x = f2bf(v.x); o.y = f2bf(v.y); o.z = f2bf(v.z); o.w = f2bf(v.w);
  }
  ((ushort4*)dst)[i] = o;
}

// ---------------------------------------------------------------------------
// K0: transpose+convert x[b][c][n] (f32) -> xT[b][n][c] (bf16), 64x64 tiles
// ---------------------------------------------------------------------------
__global__ __launch_bounds__(256) void k_transpose(const float* __restrict__ x,
                                                   u16* __restrict__ xT,
                                                   int nC, int nN) {
  __shared__ u16 tile[64 * 65];
  int b = blockIdx.z;
  int c0 = blockIdx.y * 64, n0 = blockIdx.x * 64;
  const float* xb = x + ((long)b * nC + c0) * nN + n0;
  u16* xTb = xT + ((long)b * nN + n0) * nC + c0;
  int tid = threadIdx.x;
#pragma unroll
  for (int p = 0; p < 2; ++p) {
    int u = tid + p * 256;
    int r = u >> 3, nc = (u & 7) * 8;
    const float4* srcp = (const float4*)(xb + (long)r * nN + nc);
    float4 v0 = srcp[0], v1 = srcp[1];
    int base = r * 65 + nc;
    tile[base + 0] = f2bf(v0.x); tile[base + 1] = f2bf(v0.y);
    tile[base + 2] = f2bf(v0.z); tile[base + 3] = f2bf(v0.w);
    tile[base + 4] = f2bf(v1.x); tile[base + 5] = f2bf(v1.y);
    tile[base + 6] = f2bf(v1.z); tile[base + 7] = f2bf(v1.w);
  }
  __syncthreads();
#pragma unroll
  for (int p = 0; p < 2; ++p) {
    int u = tid + p * 256;
    int nr = u >> 3, cc = (u & 7) * 8;
    __align__(16) u16 tmp[8];
#pragma unroll
    for (int j = 0; j < 8; ++j) tmp[j] = tile[(cc + j) * 65 + nr];
    *(uint4*)(xTb + (long)nr * nC + cc) = *(uint4*)(tmp);
  }
}

// ---------------------------------------------------------------------------
// gemm64: Out[M,N] = A[M,K] * B[Ncols,K]^T (+bias, relu), bf16 in, fp32 acc.
// FULL TILES ONLY. BK=64, width-16 global_load_lds, XOR k-piece swizzle
// (bank-conflict-free, verified R6: SQ_LDS_BANK_CONFLICT=0).
// XCD L2 swizzle: m-tile = blockIdx.x so the 8 blocks sharing an A-slab are
// stride-8 in dispatch order -> same XCD -> A fetched ~once (R6: A was
// fetched 8x, 399 MB/dispatch).
// BIAS_MODE: 0 none, 1 row, 2 col (bias1/bias2 split at nSplit).
// ---------------------------------------------------------------------------
template <bool OUT_F32, int BIAS_MODE, bool RELU>
__global__ __launch_bounds__(256) void k_gemm64(
    const u16* __restrict__ A, int lda, long aBS,
    const u16* __restrict__ B1, const u16* __restrict__ B2, int nSplit,
    int ldb, long bBS,
    void* __restrict__ Out, int ldo, long oBS,
    const float* __restrict__ bias1, const float* __restrict__ bias2,
    int M, int N, int K) {
  __shared__ __align__(16) u16 As[128 * 64];  // 16 KB
  __shared__ __align__(16) u16 Bs[128 * 64];  // 16 KB
  int bz = blockIdx.z;
  int m0 = blockIdx.x * 128, n0 = blockIdx.y * 128;  // XCD swizzle (see above)
  const u16* Ablk = A + (long)bz * aBS + (long)m0 * lda;
  const u16* Bblk =
      ((n0 < nSplit) ? (B1 + (long)n0 * ldb) : (B2 + (long)(n0 - nSplit) * ldb)) +
      (long)bz * bBS;
  int tid = threadIdx.x;
  int lane = tid & 63;
  int lane16 = lane & 15, quad = lane >> 4;
  int wid = tid >> 6;
  int wm = wid >> 1, wn = wid & 1;

  int rIn = lane >> 3;
  int kkSw = ((lane & 7) ^ rIn) * 8;

  floatx4 acc[4][4];
#pragma unroll
  for (int i = 0; i < 4; ++i)
#pragma unroll
    for (int j = 0; j < 4; ++j) acc[i][j] = (floatx4){0.f, 0.f, 0.f, 0.f};

  for (int k0 = 0; k0 < K; k0 += 64) {
    __syncthreads();
#pragma unroll
    for (int h = 0; h < 4; ++h) {
      int ch = wid * 4 + h;
      int r = ch * 8 + rIn;
      const u16* srcA = Ablk + (long)r * lda + k0 + kkSw;
      __builtin_amdgcn_global_load_lds(
          (const __attribute__((address_space(1))) void*)srcA,
          (__attribute__((address_space(3))) void*)&As[ch * 512], 16, 0, 0);
      const u16* srcB = Bblk + (long)r * ldb + k0 + kkSw;
      __builtin_amdgcn_global_load_lds(
          (const __attribute__((address_space(1))) void*)srcB,
          (__attribute__((address_space(3))) void*)&Bs[ch * 512], 16, 0, 0);
    }
    __syncthreads();
#pragma unroll
    for (int h2 = 0; h2 < 2; ++h2) {
      short8 af[4], bfr[4];
#pragma unroll
      for (int t = 0; t < 4; ++t) {
        int ra = wm * 64 + t * 16 + lane16;
        af[t] = *(const short8*)&As[ra * 64 + (((h2 * 4 + quad) ^ (ra & 7)) * 8)];
      }
#pragma unroll
      for (int t = 0; t < 4; ++t) {
        int rb = wn * 64 + t * 16 + lane16;
        bfr[t] = *(const short8*)&Bs[rb * 64 + (((h2 * 4 + quad) ^ (rb & 7)) * 8)];
      }
#pragma unroll
      for (int i = 0; i < 4; ++i)
#pragma unroll
        for (int j = 0; j < 4; ++j)
          acc[i][j] = __builtin_amdgcn_mfma_f32_16x16x32_bf16(af[i], bfr[j],
                                                              acc[i][j], 0, 0, 0);
    }
  }

  // epilogue: C/D layout col=lane&15, row=quad*4+reg  [m89-verified]
  const float* bcolPtr = bias1;
  int bofs = 0;
  if (BIAS_MODE == 2 && n0 >= nSplit) { bcolPtr = bias2; bofs = nSplit; }
#pragma unroll
  for (int i = 0; i < 4; ++i) {
    int rowb = m0 + wm * 64 + i * 16 + quad * 4;
#pragma unroll
    for (int j = 0; j < 4; ++j) {
      int col = n0 + wn * 64 + j * 16 + lane16;
      float bc = 0.f;
      if (BIAS_MODE == 2) bc = bcolPtr[col - bofs];
#pragma unroll
      for (int r = 0; r < 4; ++r) {
        int row = rowb + r;
        float v = acc[i][j][r];
        if (BIAS_MODE == 2) v += bc;
        if (BIAS_MODE == 1) v += bias1[row];
        if (RELU) v = fmaxf(v, 0.f);
        if (OUT_F32)
          ((float*)Out)[(long)bz * oBS + (long)row * ldo + col] = v;
        else
          ((u16*)Out)[(long)bz * oBS + (long)row * ldo + col] = f2bf(v);
      }
    }
  }
}

// ---------------------------------------------------------------------------
// K2 fused: grid (8, 2, c). y=0: f = wc2 . hT_cf^T + cf_b2
//                           y=1: scr = ws2p . hT_sc^T + scb2p
// M=128, N=1024, K=512. Same BK=64 XOR-swizzled structure.
// ---------------------------------------------------------------------------
__global__ __launch_bounds__(256) void k_k2dual(
    const u16* __restrict__ wA, const u16* __restrict__ wB,
    const u16* __restrict__ hT, u16* __restrict__ fOut, u16* __restrict__ sOut,
    const float* __restrict__ bA, const float* __restrict__ bB) {
  __shared__ __align__(16) u16 As[128 * 64];
  __shared__ __align__(16) u16 Bs[128 * 64];
  int sel = blockIdx.y, bz = blockIdx.z;
  const u16* A = sel ? wB : wA;                               // [128][512]
  const u16* Bbase = hT + (long)bz * 1048576 + (sel ? 512 : 0);
  u16* Out = (sel ? sOut : fOut) + (long)bz * 131072;
  const float* bias = sel ? bB : bA;
  int n0 = blockIdx.x * 128;
  int tid = threadIdx.x;
  int lane = tid & 63;
  int lane16 = lane & 15, quad = lane >> 4;
  int wid = tid >> 6;
  int wm = wid >> 1, wn = wid & 1;
  int rIn = lane >> 3;
  int kkSw = ((lane & 7) ^ rIn) * 8;

  floatx4 acc[4][4];
#pragma unroll
  for (int i = 0; i < 4; ++i)
#pragma unroll
    for (int j = 0; j < 4; ++j) acc[i][j] = (floatx4){0.f, 0.f, 0.f, 0.f};

  for (int k0 = 0; k0 < 512; k0 += 64) {
    __syncthreads();
#pragma unroll
    for (int h = 0; h < 4; ++h) {
      int ch = wid * 4 + h;
      int r = ch * 8 + rIn;
      const u16* srcA = A + (long)r * 512 + k0 + kkSw;
      __builtin_amdgcn_global_load_lds(
          (const __attribute__((address_space(1))) void*)srcA,
          (__attribute__((address_space(3))) void*)&As[ch * 512], 16, 0, 0);
      const u16* srcB = Bbase + (long)(n0 + r) * 1024 + k0 + kkSw;
      __builtin_amdgcn_global_load_lds(
          (const __attribute__((address_space(1))) void*)srcB,
          (__attribute__((address_space(3))) void*)&Bs[ch * 512], 16, 0, 0);
    }
    __syncthreads();
#pragma unroll
    for (int h2 = 0; h2 < 2; ++h2) {
      short8 af[4], bfr[4];
#pragma unroll
      for (int t = 0; t < 4; ++t) {
        int ra = wm * 64 + t * 16 + lane16;
        af[t] = *(const short8*)&As[ra * 64 + (((h2 * 4 + quad) ^ (ra & 7)) * 8)];
      }
#pragma unroll
      for (int t = 0; t < 4; ++t) {
        int rb = wn * 64 + t * 16 + lane16;
        bfr[t] = *(const short8*)&Bs[rb * 64 + (((h2 * 4 + quad) ^ (rb & 7)) * 8)];
      }
#pragma unroll
      for (int i = 0; i < 4; ++i)
#pragma unroll
        for (int j = 0; j < 4; ++j)
          acc[i][j] = __builtin_amdgcn_mfma_f32_16x16x32_bf16(af[i], bfr[j],
                                                              acc[i][j], 0, 0, 0);
    }
  }
#pragma unroll
  for (int i = 0; i < 4; ++i) {
    int rowb = wm * 64 + i * 16 + quad * 4;
#pragma unroll
    for (int j = 0; j < 4; ++j) {
      int col = n0 + wn * 64 + j * 16 + lane16;
#pragma unroll
      for (int r = 0; r < 4; ++r) {
        int row = rowb + r;
        Out[(long)row * 1024 + col] = f2bf(acc[i][j][r] + bias[row]);
      }
    }
  }
}

// ---------------------------------------------------------------------------
// K3: log-space Sinkhorn, one block per batch. scores bf16, 128-row stride
// (rows 0..63 valid).
// ---------------------------------------------------------------------------
__global__ __launch_bounds__(1024) void k_sinkhorn(
    const u16* __restrict__ S, const float* __restrict__ alphaPtr,
    float lmu, float lmu_bin, float lnu, float norm, u16* __restrict__ P) {
  __shared__ float u_[65];
  __shared__ float v_[1024];
  int b = blockIdx.x, tid = threadIdx.x;
  const u16* Sb = S + (long)b * 131072;
  float alpha = *alphaPtr;
  v_[tid] = 0.f;
  __syncthreads();
  int wid = tid >> 6, lane = tid & 63;
  for (int it = 0; it < 3; ++it) {
    for (int i = wid; i < 65; i += 16) {   // u-pass: wave per row
      float vals[16];
      float mx = -3.4e38f;
#pragma unroll
      for (int s = 0; s < 16; ++s) {
        int j = lane + s * 64;
        float z = (i < 64 ? bf2f(Sb[i * 1024 + j]) : alpha) + v_[j];
        vals[s] = z;
        mx = fmaxf(mx, z);
      }
#pragma unroll
      for (int off = 32; off > 0; off >>= 1) mx = fmaxf(mx, __shfl_xor(mx, off));
      float sum = 0.f;
#pragma unroll
      for (int s = 0; s < 16; ++s) sum += __expf(vals[s] - mx);
#pragma unroll
      for (int off = 32; off > 0; off >>= 1) sum += __shfl_xor(sum, off);
      if (lane == 0) u_[i] = (i < 64 ? lmu : lmu_bin) - (mx + __logf(sum));
    }
    __syncthreads();
    {  // v-pass: thread per column, two-pass LSE over m=65
      float mx = alpha + u_[64];
#pragma unroll 8
      for (int i = 0; i < 64; ++i)
        mx = fmaxf(mx, bf2f(Sb[i * 1024 + tid]) + u_[i]);
      float sum = __expf(alpha + u_[64] - mx);
#pragma unroll 8
      for (int i = 0; i < 64; ++i)
        sum += __expf(bf2f(Sb[i * 1024 + tid]) + u_[i] - mx);
      v_[tid] = lnu - (mx + __logf(sum));
    }
    __syncthreads();
  }
  float vj = v_[tid];
  u16* Pb = P + (long)b * 65536;
#pragma unroll 8
  for (int i = 0; i < 64; ++i) {
    float z = bf2f(Sb[i * 1024 + tid]) + u_[i] + vj - norm;
    Pb[i * 1024 + tid] = f2bf(__expf(fminf(z, 1.0f)));  // z<=0 mathematically
  }
}

// ---------------------------------------------------------------------------
// K4: split-K agg partials. aggP[kc][b][128][64] = f[b,128,ks] P[b,64,ks]^T
// ---------------------------------------------------------------------------
__global__ __launch_bounds__(256) void k_agg(const u16* __restrict__ f,
                                             const u16* __restrict__ P,
                                             float* __restrict__ aggP) {
  __shared__ __align__(16) u16 Fs[128 * 32];
  __shared__ __align__(16) u16 Ps[64 * 32];
  int bz = blockIdx.z, kc = blockIdx.x;
  const u16* Fb = f + (long)bz * 128 * 1024;
  const u16* Pb = P + (long)bz * 64 * 1024;
  int tid = threadIdx.x, wid = tid >> 6, lane = tid & 63;
  int lane16 = lane & 15, quad = lane >> 4;
  int rA0 = lane >> 2, kk = (lane & 3) * 8;

  floatx4 acc[2][4];
#pragma unroll
  for (int i = 0; i < 2; ++i)
#pragma unroll
    for (int j = 0; j < 4; ++j) acc[i][j] = (floatx4){0.f, 0.f, 0.f, 0.f};

  for (int k0 = kc * 256; k0 < kc * 256 + 256; k0 += 32) {
    __syncthreads();
#pragma unroll
    for (int h = 0; h < 2; ++h) {
      int ch = wid * 2 + h;
      int r = ch * 16 + rA0;
      const u16* srcF = Fb + (long)r * 1024 + k0 + kk;
      __builtin_amdgcn_global_load_lds(
          (const __attribute__((address_space(1))) void*)srcF,
          (__attribute__((address_space(3))) void*)&Fs[ch * 512], 16, 0, 0);
    }
    {
      int r = wid * 16 + rA0;
      const u16* srcP = Pb + (long)r * 1024 + k0 + kk;
      __builtin_amdgcn_global_load_lds(
          (const __attribute__((address_space(1))) void*)srcP,
          (__attribute__((address_space(3))) void*)&Ps[wid * 512], 16, 0, 0);
    }
    __syncthreads();
    short8 af[2], bfr[4];
#pragma unroll
    for (int t = 0; t < 2; ++t)
      af[t] = *(const short8*)&Fs[(wid * 32 + t * 16 + lane16) * 32 + quad * 8];
#pragma unroll
    for (int j = 0; j < 4; ++j)
      bfr[j] = *(const short8*)&Ps[(j * 16 + lane16) * 32 + quad * 8];
#pragma unroll
    for (int i = 0; i < 2; ++i)
#pragma unroll
      for (int j = 0; j < 4; ++j)
        acc[i][j] = __builtin_amdgcn_mfma_f32_16x16x32_bf16(af[i], bfr[j],
                                                            acc[i][j], 0, 0, 0);
  }
  float* ab = aggP + ((long)kc * 32 + bz) * 8192;
#pragma unroll
  for (int i = 0; i < 2; ++i)
#pragma unroll
    for (int j = 0; j < 4; ++j)
#pragma unroll
      for (int r = 0; r < 4; ++r) {
        int row = wid * 32 + i * 16 + quad * 4 + r;
        int col = j * 16 + lane16;
        ab[row * 64 + col] = acc[i][j][r];
      }
}

// ---------------------------------------------------------------------------
// token MLP, parallelized.
// ---------------------------------------------------------------------------
DEVINL float waveSum(float x) {
#pragma unroll
  for (int off = 32; off > 0; off >>= 1) x += __shfl_xor(x, off);
  return x;
}

__global__ __launch_bounds__(256) void k_mlp1(const float* __restrict__ t,
                                              const float* __restrict__ w1,
                                              const float* __restrict__ b1,
                                              float* __restrict__ h1) {
  __shared__ float tl[1536];
  int b = blockIdx.y, og = blockIdx.x;
  int tid = threadIdx.x, wid = tid >> 6, lane = tid & 63;
  for (int i = tid; i < 1536; i += 256) tl[i] = t[b * 1536 + i];
  __syncthreads();
#pragma unroll 4
  for (int oi = 0; oi < 16; ++oi) {
    int o = og * 64 + wid * 16 + oi;
    const float* wr = w1 + (long)o * 1536;
    float acc = 0.f;
#pragma unroll
    for (int s = 0; s < 24; ++s) { int c = lane + s * 64; acc += tl[c] * wr[c]; }
    acc = waveSum(acc);
    if (lane == 0) h1[b * 512 + o] = fmaxf(acc + b1[o], 0.f);
  }
}

__global__ __launch_bounds__(256) void k_mlp2(const float* __restrict__ h1,
                                              const float* __restrict__ w2,
                                              const float* __restrict__ b2,
                                              float* __restrict__ tk) {
  __shared__ float hl[512];
  int b = blockIdx.y, og = blockIdx.x;
  int tid = threadIdx.x, wid = tid >> 6, lane = tid & 63;
  for (int i = tid; i < 512; i += 256) hl[i] = h1[b * 512 + i];
  __syncthreads();
#pragma unroll 4
  for (int oi = 0; oi < 16; ++oi) {
    int o = og * 64 + wid * 16 + oi;
    const float* wr = w2 + (long)o * 512;
    float acc = 0.f;
#pragma unroll
    for (int s = 0; s < 8; ++s) { int c = lane + s * 64; acc += hl[c] * wr[c]; }
    acc = waveSum(acc);
    if (lane == 0) tk[b * 256 + o] = acc + b2[o];
  }
}

// ---------------------------------------------------------------------------
// K5: norms + output.
// ---------------------------------------------------------------------------
DEVINL float blockSum256(float x, float* red) {
#pragma unroll
  for (int off = 32; off > 0; off >>= 1) x += __shfl_xor(x, off);
  int wid = threadIdx.x >> 6;
  __syncthreads();
  if ((threadIdx.x & 63) == 0) red[wid] = x;
  __syncthreads();
  return red[0] + red[1] + red[2] + red[3];
}

__global__ __launch_bounds__(256) void k_norms(const float* __restrict__ tk,
                                               const float* __restrict__ aggP,
                                               float* __restrict__ out) {
  __shared__ float asum[8192];
  __shared__ float cn[64];
  __shared__ float red[4];
  int b = blockIdx.x, tid = threadIdx.x;
  const float* a0 = aggP + (long)b * 8192;
  for (int idx = tid; idx < 8192; idx += 256)
    asum[idx] = a0[idx] + a0[32 * 8192 + idx] + a0[64 * 8192 + idx] +
                a0[96 * 8192 + idx];
  __syncthreads();
  float tkv = tk[b * 256 + tid];
  float tss = blockSum256(tkv * tkv, red);
  float tn = fmaxf(sqrtf(tss), 1e-12f);
  if (tid < 64) {
    float s = 0.f;
    for (int l = 0; l < 128; ++l) { float a = asum[l * 64 + tid]; s += a * a; }
    cn[tid] = fmaxf(sqrtf(s), 1e-12f);
  }
  __syncthreads();
  float gs = (tkv / tn) * (tkv / tn);
  for (int idx = tid; idx < 8192; idx += 256) {
    float a = asum[idx] / cn[idx & 63];
    gs += a * a;
  }
  float G = blockSum256(gs, red);
  float inv = 1.f / fmaxf(sqrtf(G), 1e-12f);
  float* ob = out + (long)b * 8448;
  ob[tid] = tkv / tn * inv;
  for (int idx = tid; idx < 8192; idx += 256)
    ob[256 + idx] = asum[idx] / cn[idx & 63] * inv;
}

// ---------------------------------------------------------------------------
extern "C" void kernel_launch(void* const* d_in, const int* in_sizes, int n_in,
                              void* d_out, int out_size, void* d_ws,
                              size_t ws_size, hipStream_t stream) {
  const float* x = (const float*)d_in[0];
  const float* t = (const float*)d_in[1];
  const float* cf_w1 = (const float*)d_in[2];
  const float* cf_b1 = (const float*)d_in[3];
  const float* cf_w2 = (const float*)d_in[4];
  const float* cf_b2 = (const float*)d_in[5];
  const float* sc_w1 = (const float*)d_in[6];
  const float* sc_b1 = (const float*)d_in[7];
  const float* sc_w2 = (const float*)d_in[8];
  const float* sc_b2 = (const float*)d_in[9];
  const float* tk_w1 = (const float*)d_in[10];
  const float* tk_b1 = (const float*)d_in[11];
  const float* tk_w2 = (const float*)d_in[12];
  const float* tk_b2 = (const float*)d_in[13];
  const float* dust = (const float*)d_in[14];
  float* out = (float*)d_out;

  // workspace layout (all 16B-multiples)
  char* ws = (char*)d_ws;
  size_t off = 0;
  u16* wc1 = (u16*)(ws + off); off += (size_t)512 * 1536 * 2;        // cf_w1 bf16
  u16* ws1 = (u16*)(ws + off); off += (size_t)512 * 1536 * 2;        // sc_w1 bf16
  u16* wc2 = (u16*)(ws + off); off += (size_t)128 * 512 * 2;         // cf_w2 bf16
  u16* ws2p = (u16*)(ws + off); off += (size_t)128 * 512 * 2;        // sc_w2 padded
  float* scb2p = (float*)(ws + off); off += (size_t)128 * 4;         // sc_b2 padded
  u16* f = (u16*)(ws + off);   off += (size_t)32 * 128 * 1024 * 2;   // 8 MB
  u16* scr = (u16*)(ws + off); off += (size_t)32 * 128 * 1024 * 2;   // 8 MB
  u16* P = (u16*)(ws + off);   off += (size_t)32 * 64 * 1024 * 2;    // 4 MB
  float* aggP = (float*)(ws + off); off += (size_t)4 * 32 * 128 * 64 * 4; // 4 MB
  float* h1ws = (float*)(ws + off); off += (size_t)32 * 512 * 4;     // 64 KB
  float* tkws = (float*)(ws + off); off += (size_t)32 * 256 * 4;     // 32 KB
  size_t fixed = off;
  size_t perB = (size_t)1024 * 1536 * 2 + (size_t)1024 * 1024 * 2;   // xT+hT
  int c = 1;
  const int cands[6] = {32, 16, 8, 4, 2, 1};
  for (int k = 0; k < 6; ++k)
    if (fixed + (size_t)cands[k] * perB <= ws_size) { c = cands[k]; break; }
  u16* xT = (u16*)(ws + fixed);
  u16* hT = (u16*)(ws + fixed + (size_t)c * 1024 * 1536 * 2);

  // weight prep (one dispatch)
  k_prep<<<dim3(768, 5), 256, 0, stream>>>(cf_w1, wc1, sc_w1, ws1, cf_w2, wc2,
                                           sc_w2, ws2p, sc_b2, scb2p);

  // token MLP (independent of the conv path — launch early)
  k_mlp1<<<dim3(8, 32), 256, 0, stream>>>(t, tk_w1, tk_b1, h1ws);
  k_mlp2<<<dim3(4, 32), 256, 0, stream>>>(h1ws, tk_w2, tk_b2, tkws);

  float norm = -logf(1088.f);          // -log(m+n), m=64 n=1024
  float lmu = norm;
  float lmu_bin = logf(960.f) + norm;  // log(n-m) + norm
  float lnu = norm;

  for (int cb = 0; cb < 32; cb += c) {
    // K0: x[b][c][n] f32 -> xT[b][n][c] bf16
    k_transpose<<<dim3(16, 24, c), 256, 0, stream>>>(
        x + (size_t)cb * 1536 * 1024, xT, 1536, 1024);
    // K1: hT[b][n][o] = relu(xT . W1^T + b1), fused cf(o<512) + sc(o>=512)
    k_gemm64<false, 2, true><<<dim3(8, 8, c), 256, 0, stream>>>(
        xT, 1536, (long)1024 * 1536,
        wc1, ws1, 512, 1536, 0,
        hT, 1024, (long)1024 * 1024,
        cf_b1, sc_b1, 1024, 1024, 1536);
    // K2 fused: f + scores in one dispatch
    k_k2dual<<<dim3(8, 2, c), 256, 0, stream>>>(
        wc2, ws2p, hT, f + (size_t)cb * 131072, scr + (size_t)cb * 131072,
        cf_b2, scb2p);
  }
  // K3: Sinkhorn -> P bf16 [b][64][1024]
  k_sinkhorn<<<32, 1024, 0, stream>>>(scr, dust, lmu, lmu_bin, lnu, norm, P);
  // K4: split-K agg partials [4][32][128][64]
  k_agg<<<dim3(4, 1, 32), 256, 0, stream>>>(f, P, aggP);
  // K5: norms + output
  k_norms<<<32, 256, 0, stream>>>(tkws, aggP, out);
}